// Round 4
// baseline (508.033 us; speedup 1.0000x reference)
//
#include <hip/hip_runtime.h>
#include <cstdint>
#include <cstddef>

#define DEVFN __device__ __forceinline__

typedef short bf16x8 __attribute__((ext_vector_type(8)));
typedef float f32x4  __attribute__((ext_vector_type(4)));
typedef int   i32x4  __attribute__((ext_vector_type(4)));

// problem constants
static constexpr int NTOK  = 64 * 196;   // 12544  (= 98 * 128)
static constexpr int DMODEL= 768;
static constexpr int NHEAD = 12;
static constexpr int NQKV  = 2304;       // 3*768 (= 18 * 128)
static constexpr int MMLP  = 3072;       // 4*768 (= 24 * 128)
static constexpr int SEQ   = 196;
static constexpr int NBATCH= 64;

// scale slots (absmax bits, atomicMax on uint reinterpretation of fp32)
enum { SL_LN1=0, SL_WQKV=1, SL_CTX=2, SL_WO=3, SL_LN2=4, SL_W1=5, SL_GELU=6, SL_W2=7 };

// ---- scattered absmax slots: 64 shadow copies per logical slot, 256B apart ----
static constexpr int NSH       = 64;     // shadow buckets per slot
static constexpr int SH_STRIDE = 64;     // uints between buckets (256 B lines)
static constexpr int SLOTS_U32 = NSH * SH_STRIDE;   // 4096 uints = 16 KB

DEVFN float bf2f(unsigned short u){ return __uint_as_float(((unsigned)u) << 16); }
DEVFN unsigned short f2bf(float f){            // round-to-nearest-even
  unsigned u = __float_as_uint(f);
  u += 0x7fffu + ((u >> 16) & 1u);
  return (unsigned short)(u >> 16);
}
DEVFN void split_bf(float v, unsigned short& hi, unsigned short& lo){
  hi = f2bf(v);
  lo = f2bf(v - bf2f(hi));                     // v-hi is exact in fp32
}
DEVFN float slot_absmax(const unsigned* __restrict__ slots, int slot){
  unsigned m = 0u;
#pragma unroll
  for (int j = 0; j < NSH; j++){
    unsigned u = slots[j * SH_STRIDE + slot];  // uniform scalar loads, L2-hot
    m = (u > m) ? u : m;                       // bits >=0: uint order == float order
  }
  return __uint_as_float(m);
}
DEVFN float slot_scale(const unsigned* __restrict__ slots, int slot){
  return fmaxf(slot_absmax(slots, slot) / 127.0f, 1e-8f);   // exact match to ref: max/127.0
}
DEVFN void scatter_amax(unsigned* slots, int slot, unsigned bucket, float v){
  atomicMax(slots + (bucket & (NSH - 1)) * SH_STRIDE + slot, __float_as_uint(v));
}
DEVFN float quantval(float x, float s){        // integer-valued quantized result
  float q = rintf(x / s);                      // RNE, matches jnp.round
  return fminf(fmaxf(q, -128.0f), 127.0f);
}
DEVFN unsigned pack4(float a, float b, float c, float d){
  return  ((unsigned)(unsigned char)(char)(int)a)
        | ((unsigned)(unsigned char)(char)(int)b << 8)
        | ((unsigned)(unsigned char)(char)(int)c << 16)
        | ((unsigned)(unsigned char)(char)(int)d << 24);
}
// exact-GELU with branch-free A&S 7.1.26 erf (max abs err 1.5e-7, invisible
// under the immediate bf16 rounding of the result).
DEVFN float gelu_fast(float v){
  float s  = v * 0.70710678118654752f;
  float ax = fabsf(s);
  float t  = __builtin_amdgcn_rcpf(fmaf(0.3275911f, ax, 1.0f));
  float p  = t * fmaf(t, fmaf(t, fmaf(t, fmaf(t, 1.061405429f, -1.453152027f),
                                      1.421413741f), -0.284496736f), 0.254829592f);
  float er = fmaf(-p, __expf(-ax * ax), 1.0f);           // erf(|s|) in [0,1)
  unsigned sgn = __float_as_uint(s) & 0x80000000u;
  er = __uint_as_float(__float_as_uint(er) | sgn);
  return 0.5f * v * (1.0f + er);
}
DEVFN f32x4 mfma16(bf16x8 a, bf16x8 b, f32x4 c){
  return __builtin_amdgcn_mfma_f32_16x16x32_bf16(a, b, c, 0, 0, 0);
}
DEVFN i32x4 mfma16i8(i32x4 a, i32x4 b, i32x4 c){
  return __builtin_amdgcn_mfma_i32_16x16x64_i8(a, b, c, 0, 0, 0);
}
DEVFN void async_ld16(const void* g, void* lds){
  __builtin_amdgcn_global_load_lds((const __attribute__((address_space(1))) void*)g,
                                   (__attribute__((address_space(3))) void*)lds, 16, 0, 0);
}
// V^T LDS layout: stride 256 ushorts + XOR swizzle on s-bits 3..5.
DEVFN int vidx(int d, int s){
  return d * 256 + (s ^ (((d ^ (d >> 2)) & 7) << 3));
}

// ---------------- init scale slots ----------------
__global__ void k_init(unsigned* slots){
  int i = blockIdx.x * blockDim.x + threadIdx.x;
  if (i < SLOTS_U32) slots[i] = 0u;
}

// ---------------- fused absmax of the 4 weight tensors (1 launch) ----------------
__global__ void k_absmax4(const float* __restrict__ x0, const float* __restrict__ x1,
                          const float* __restrict__ x2, const float* __restrict__ x3,
                          unsigned* slots){
  int bid = blockIdx.x;
  const float* x; int n4, slot, b0, nb;
  if (bid < 256)      { x = x0; n4 = DMODEL * NQKV  / 4; slot = SL_WQKV; b0 = 0;   nb = 256; }
  else if (bid < 384) { x = x1; n4 = DMODEL * DMODEL/ 4; slot = SL_WO;   b0 = 256; nb = 128; }
  else if (bid < 640) { x = x2; n4 = DMODEL * MMLP  / 4; slot = SL_W1;   b0 = 384; nb = 256; }
  else                { x = x3; n4 = MMLP   * DMODEL/ 4; slot = SL_W2;   b0 = 640; nb = 256; }
  int lb = bid - b0;
  float m = 0.f;
  const float4* x4 = (const float4*)x;
  int stride = nb * blockDim.x;
  for (int j = lb * blockDim.x + threadIdx.x; j < n4; j += stride){
    float4 v = x4[j];
    m = fmaxf(m, fmaxf(fmaxf(fabsf(v.x), fabsf(v.y)), fmaxf(fabsf(v.z), fabsf(v.w))));
  }
  for (int off = 32; off; off >>= 1) m = fmaxf(m, __shfl_xor(m, off));
  __shared__ float wm[4];
  int lane = threadIdx.x & 63, w = threadIdx.x >> 6;
  if (lane == 0) wm[w] = m;
  __syncthreads();
  if (threadIdx.x == 0){
    float bm = fmaxf(fmaxf(wm[0], wm[1]), fmaxf(wm[2], wm[3]));
    scatter_amax(slots, slot, bid, bm);
  }
}

// ---------------- quantize weight (K x N fp32) -> transposed int8 (N x K) ----------------
__global__ void k_quant_transpose(const float* __restrict__ w, char* __restrict__ wt,
                                  int K, int N, const unsigned* __restrict__ slots, int slot){
  __shared__ float tile[32][33];
  float s = slot_scale(slots, slot);
  int n0 = blockIdx.x * 32, k0 = blockIdx.y * 32;
  int tx = threadIdx.x & 31, ty = threadIdx.x >> 5;   // 256 threads: ty 0..7
#pragma unroll
  for (int i = 0; i < 4; i++){
    int k = k0 + ty + i * 8;
    float v = w[(size_t)k * N + n0 + tx];
    tile[ty + i * 8][tx] = quantval(v, s);
  }
  __syncthreads();
  // write: thread -> (n = tid>>3, kg = tid&7), 4 consecutive k bytes
  int n = threadIdx.x >> 3, kg = threadIdx.x & 7;
  unsigned o = pack4(tile[kg * 4 + 0][n], tile[kg * 4 + 1][n],
                     tile[kg * 4 + 2][n], tile[kg * 4 + 3][n]);
  *(unsigned*)(wt + (size_t)(n0 + n) * K + k0 + kg * 4) = o;
}

// ---------------- layernorm (rows of 768) + absmax ----------------
__global__ void k_layernorm(const float* __restrict__ x, const float* __restrict__ g,
                            const float* __restrict__ b, float* __restrict__ out,
                            unsigned* slots, int slot){
  int w = threadIdx.x >> 6, lane = threadIdx.x & 63;
  int row = blockIdx.x * 4 + w;
  const float4* xr = (const float4*)(x + (size_t)row * DMODEL);
  float4 v[3];
  float sum = 0.f;
#pragma unroll
  for (int i = 0; i < 3; i++){ v[i] = xr[i * 64 + lane]; sum += v[i].x + v[i].y + v[i].z + v[i].w; }
  for (int off = 32; off; off >>= 1) sum += __shfl_xor(sum, off);
  float mu = sum * (1.0f / 768.0f);
  float vs = 0.f;
#pragma unroll
  for (int i = 0; i < 3; i++){
    float dx = v[i].x - mu, dy = v[i].y - mu, dz = v[i].z - mu, dw = v[i].w - mu;
    vs += dx * dx + dy * dy + dz * dz + dw * dw;
  }
  for (int off = 32; off; off >>= 1) vs += __shfl_xor(vs, off);
  float inv = 1.0f / sqrtf(vs * (1.0f / 768.0f) + 1e-5f);
  const float4* g4 = (const float4*)g; const float4* b4 = (const float4*)b;
  float4* o4 = (float4*)(out + (size_t)row * DMODEL);
  float am = 0.f;
#pragma unroll
  for (int i = 0; i < 3; i++){
    float4 gg = g4[i * 64 + lane], bb = b4[i * 64 + lane], o;
    o.x = (v[i].x - mu) * inv * gg.x + bb.x;
    o.y = (v[i].y - mu) * inv * gg.y + bb.y;
    o.z = (v[i].z - mu) * inv * gg.z + bb.z;
    o.w = (v[i].w - mu) * inv * gg.w + bb.w;
    am = fmaxf(am, fmaxf(fmaxf(fabsf(o.x), fabsf(o.y)), fmaxf(fabsf(o.z), fabsf(o.w))));
    o4[i * 64 + lane] = o;
  }
  for (int off = 32; off; off >>= 1) am = fmaxf(am, __shfl_xor(am, off));
  __shared__ float am4[4];
  if (lane == 0) am4[w] = am;
  __syncthreads();
  if (threadIdx.x == 0){
    float bm = fmaxf(fmaxf(am4[0], am4[1]), fmaxf(am4[2], am4[3]));
    scatter_amax(slots, slot, blockIdx.x, bm);
  }
}

// ---------------- quantize fp32 activations -> packed int8 ----------------
__global__ void k_quant_act(const float* __restrict__ x, unsigned* __restrict__ out,
                            int n4, const unsigned* __restrict__ slots, int slot){
  float s = slot_scale(slots, slot);
  const float4* x4 = (const float4*)x;
  int stride = gridDim.x * blockDim.x;
  for (int j = blockIdx.x * blockDim.x + threadIdx.x; j < n4; j += stride){
    float4 v = x4[j];
    out[j] = pack4(quantval(v.x, s), quantval(v.y, s), quantval(v.z, s), quantval(v.w, s));
  }
}

// ---------------- quantize bf16 activations -> packed int8 ----------------
__global__ void k_quant_bf16_i8(const unsigned short* __restrict__ x, unsigned* __restrict__ out,
                                int n4, const unsigned* __restrict__ slots, int slot){
  float s = slot_scale(slots, slot);
  const ushort4* x4 = (const ushort4*)x;
  int stride = gridDim.x * blockDim.x;
  for (int j = blockIdx.x * blockDim.x + threadIdx.x; j < n4; j += stride){
    ushort4 v = x4[j];
    out[j] = pack4(quantval(bf2f(v.x), s), quantval(bf2f(v.y), s),
                   quantval(bf2f(v.z), s), quantval(bf2f(v.w), s));
  }
}

// ---------------- int8 GEMM: C[M,N] = sa*sb * (A[M,K] @ Bt[N,K]^T) + bias (+res / gelu) ---------
template<int EPI>
__launch_bounds__(256, 4)
__global__ void k_gemm(const char* __restrict__ A,    // M x K int8
                       const char* __restrict__ Bt,   // N x K int8
                       const float* __restrict__ bias,
                       const float* __restrict__ res,
                       float* __restrict__ Cf,
                       unsigned short* __restrict__ Cb,
                       const unsigned* __restrict__ slots, int sa_slot, int sb_slot,
                       unsigned* gmax_slots, int gmax_slot,
                       int M, int N, int K)
{
  __shared__ __align__(16) char smem[32768];
  __shared__ float gm4[4];
  const int tid  = threadIdx.x;
  const int lane = tid & 63;
  const int wv   = tid >> 6;        // 0..3
  const int wx   = wv & 1, wy = wv >> 1;
  const int quad = lane >> 4;
  const int l16  = lane & 15;
  const int m0 = blockIdx.y * 128, n0 = blockIdx.x * 128;

  auto issue = [&](int k0, int buf){
#pragma unroll
    for (int i = 0; i < 2; i++){     // A tile: 512 chunks of 16B (row = c>>2, q = c&3)
      int c = tid + i * 256;
      int row = c >> 2, q = c & 3;
      int qs = (q - ((row + (row >> 2)) & 3)) & 3;   // inverse chunk rotation
      async_ld16(A + (size_t)(m0 + row) * K + k0 + qs * 16,
                 smem + buf * 8192 + (i * 256 + wv * 64) * 16);
    }
#pragma unroll
    for (int i = 0; i < 2; i++){     // B tile
      int c = tid + i * 256;
      int row = c >> 2, q = c & 3;
      int qs = (q - ((row + (row >> 2)) & 3)) & 3;
      async_ld16(Bt + (size_t)(n0 + row) * K + k0 + qs * 16,
                 smem + 16384 + buf * 8192 + (i * 256 + wv * 64) * 16);
    }
  };

  i32x4 acc[4][4] = {};
  const int nk = K >> 6;
  issue(0, 0);

  const int ch = (((quad + (l16 & 3) + (l16 >> 2)) & 3)) * 16;

  for (int k = 0; k < nk; k++){
    const int cur = k & 1;
    if (k + 1 < nk){
      issue((k + 1) << 6, cur ^ 1);                       // prefetch next tile
      asm volatile("s_waitcnt vmcnt(4)" ::: "memory");    // tile-k loads landed; k+1 in flight
    } else {
      asm volatile("s_waitcnt vmcnt(0)" ::: "memory");
    }
    asm volatile("s_barrier" ::: "memory");               // tile-k visible to all waves

    const char* Ab = smem + cur * 8192;
    const char* Bb = smem + 16384 + cur * 8192;
    i32x4 af[4], bfr[4];
#pragma unroll
    for (int i = 0; i < 4; i++)
      af[i] = *(const i32x4*)(Ab + (wy * 64 + i * 16 + l16) * 64 + ch);
#pragma unroll
    for (int j = 0; j < 4; j++)
      bfr[j] = *(const i32x4*)(Bb + (wx * 64 + j * 16 + l16) * 64 + ch);
    asm volatile("s_waitcnt lgkmcnt(0)" ::: "memory");    // frags in regs
    asm volatile("s_barrier" ::: "memory");               // all reads of cur done

#pragma unroll
    for (int i = 0; i < 4; i++)
#pragma unroll
      for (int j = 0; j < 4; j++)
        acc[i][j] = mfma16i8(af[i], bfr[j], acc[i][j]);
  }
  __syncthreads();   // all waves out of the K-loop before stage overlay is used

  // ---- epilogue: 4 slices of 32 rows; LDS transpose -> coalesced wide loads/stores ----
  float (*stage)[132] = (float (*)[132])smem;   // 16896 B, overlays dead tile buffers
  const float sc = slot_scale(slots, sa_slot) * slot_scale(slots, sb_slot);
  const int col4 = (tid & 31) * 4;           // 0..124
  const int gc   = n0 + col4;
  const float4 bb = *(const float4*)&bias[gc];
  float gmax = 0.f;
#pragma unroll
  for (int i = 0; i < 4; i++){
#pragma unroll
    for (int j = 0; j < 4; j++)
#pragma unroll
      for (int r = 0; r < 4; r++)
        stage[wy * 16 + quad * 4 + r][wx * 64 + j * 16 + l16] = (float)acc[i][j][r];
    __syncthreads();
#pragma unroll
    for (int rr = 0; rr < 4; rr++){
      const int rl = rr * 8 + (tid >> 5);                       // 0..31
      const int gm = m0 + ((rl >> 4) * 64) + i * 16 + (rl & 15);
      float4 v = *(const float4*)&stage[rl][col4];
      v.x = v.x * sc + bb.x; v.y = v.y * sc + bb.y;
      v.z = v.z * sc + bb.z; v.w = v.w * sc + bb.w;
      if constexpr (EPI == 1){
        float4 rv = *(const float4*)&res[(size_t)gm * N + gc];
        v.x += rv.x; v.y += rv.y; v.z += rv.z; v.w += rv.w;
        *(float4*)&Cf[(size_t)gm * N + gc] = v;
      } else if constexpr (EPI == 2){
        float g0 = gelu_fast(v.x);
        float g1 = gelu_fast(v.y);
        float g2 = gelu_fast(v.z);
        float g3 = gelu_fast(v.w);
        gmax = fmaxf(gmax, fmaxf(fmaxf(fabsf(g0), fabsf(g1)), fmaxf(fabsf(g2), fabsf(g3))));
        ushort4 o = {f2bf(g0), f2bf(g1), f2bf(g2), f2bf(g3)};
        *(ushort4*)&Cb[(size_t)gm * N + gc] = o;
      } else {
        *(float4*)&Cf[(size_t)gm * N + gc] = v;
      }
    }
    __syncthreads();
  }
  if constexpr (EPI == 2){
    for (int off = 32; off; off >>= 1) gmax = fmaxf(gmax, __shfl_xor(gmax, off));
    if (lane == 0) gm4[wv] = gmax;
    __syncthreads();
    if (tid == 0){
      float bm = fmaxf(fmaxf(gm4[0], gm4[1]), fmaxf(gm4[2], gm4[3]));
      scatter_amax(gmax_slots, gmax_slot, blockIdx.x + blockIdx.y * gridDim.x, bm);
    }
  }
}

// ---------------- attention: one block per (b,h), 8 waves, q-tile-PAIRED main loop -------------
// Wave w handles q-tiles {w, w+8} TOGETHER: every K-fragment and V-fragment ds_read is shared
// by both tiles' MFMAs (LDS-pipe is the block's bottleneck resource; this halves the two
// dominant b128 read streams).
__launch_bounds__(512, 2)
__global__ void k_attention(const float* __restrict__ qkv, float* __restrict__ ctx,
                            unsigned* slots){
  __shared__ __align__(16) unsigned short Khi[208 * 72], Klo[208 * 72];   // 59,904 B
  __shared__ __align__(16) unsigned short Vhi[64 * 256], Vlo[64 * 256];   // 65,536 B (swizzled)
  __shared__ __align__(16) unsigned short Ps[8][2][16 * 40];              // 20,480 B (per-wave hi/lo)
  __shared__ float gm8[8];

  const int bh = blockIdx.x;
  const int b = bh / NHEAD, h = bh % NHEAD;
  const float* base = qkv + (size_t)b * SEQ * NQKV;
  const int tid = threadIdx.x, lane = tid & 63, wv = tid >> 6;
  const int quad = lane >> 4, l16 = lane & 15;

  // ---- prefetch ALL K/V global data into registers, then convert+write LDS ----
  float4 kreg[7], vreg[8];
#pragma unroll
  for (int i = 0; i < 7; i++){
    int idx = tid + i * 512;                  // K: 208*16 = 3328 chunks
    int r = idx >> 4, c4 = (idx & 15) * 4;
    float4 v = {0.f, 0.f, 0.f, 0.f};
    if (idx < 208 * 16 && r < SEQ)
      v = *(const float4*)(base + (size_t)r * NQKV + DMODEL + h * 64 + c4);
    kreg[i] = v;
  }
#pragma unroll
  for (int i = 0; i < 8; i++){
    int idx = tid + i * 512;                  // V: 232*16 = 3712 chunks (incl. zero pad)
    int s = idx >> 4, dg = (idx & 15) * 4;
    float4 v = {0.f, 0.f, 0.f, 0.f};
    if (idx < 232 * 16 && s < SEQ)
      v = *(const float4*)(base + (size_t)s * NQKV + 2 * DMODEL + h * 64 + dg);
    vreg[i] = v;
  }
#pragma unroll
  for (int i = 0; i < 7; i++){
    int idx = tid + i * 512;
    if (idx < 208 * 16){
      int r = idx >> 4, c4 = (idx & 15) * 4;
      float4 v = kreg[i];
      unsigned short h0,l0,h1,l1,h2,l2,h3,l3;
      split_bf(v.x, h0, l0); split_bf(v.y, h1, l1); split_bf(v.z, h2, l2); split_bf(v.w, h3, l3);
      ushort4 hs = {h0, h1, h2, h3}, ls = {l0, l1, l2, l3};
      *(ushort4*)(Khi + r * 72 + c4) = hs;
      *(ushort4*)(Klo + r * 72 + c4) = ls;
    }
  }
#pragma unroll
  for (int i = 0; i < 8; i++){
    int idx = tid + i * 512;
    if (idx < 232 * 16){
      int s = idx >> 4, dg = (idx & 15) * 4;
      float4 v = vreg[i];
      unsigned short hi, lo;
      split_bf(v.x, hi, lo); Vhi[vidx(dg + 0, s)] = hi; Vlo[vidx(dg + 0, s)] = lo;
      split_bf(v.y, hi, lo); Vhi[vidx(dg + 1, s)] = hi; Vlo[vidx(dg + 1, s)] = lo;
      split_bf(v.z, hi, lo); Vhi[vidx(dg + 2, s)] = hi; Vlo[vidx(dg + 2, s)] = lo;
      split_bf(v.w, hi, lo); Vhi[vidx(dg + 3, s)] = hi; Vlo[vidx(dg + 3, s)] = lo;
    }
  }
  __syncthreads();    // the ONLY full-block barrier in the main body

  unsigned short* PsH = &Ps[wv][0][0];
  unsigned short* PsL = &Ps[wv][1][0];

  float gmax = 0.f;
  const int qt0 = wv, qt1 = wv + 8;
  const bool has2 = (qt1 < 13);     // waves 0..4 run a pair, 5..7 a single tile

  // ---- Q fragments for both tiles (A-layout: m=l16, k=quad*8+j), split hi/lo ----
  bf16x8 aqh0[2], aql0[2], aqh1[2], aql1[2];
  {
    const int sq0 = qt0 * 16 + l16;                 // qt0<=7 -> always < 196
    const float* q0r = base + (size_t)sq0 * NQKV + h * 64;
    const int sq1 = qt1 * 16 + l16;
    const bool v1 = has2 && (sq1 < SEQ);
    const float* q1r = base + (size_t)(v1 ? sq1 : 0) * NQKV + h * 64;
#pragma unroll
    for (int ks = 0; ks < 2; ks++){
      float4 a0 = *(const float4*)(q0r + ks * 32 + quad * 8);
      float4 a1 = *(const float4*)(q0r + ks * 32 + quad * 8 + 4);
      float vv[8] = {a0.x, a0.y, a0.z, a0.w, a1.x, a1.y, a1.z, a1.w};
#pragma unroll
      for (int j = 0; j < 8; j++){
        unsigned short hi, lo; split_bf(vv[j], hi, lo);
        aqh0[ks][j] = (short)hi; aql0[ks][j] = (short)lo;
      }
      float4 b0 = {0,0,0,0}, b1 = {0,0,0,0};
      if (v1){
        b0 = *(const float4*)(q1r + ks * 32 + quad * 8);
        b1 = *(const float4*)(q1r + ks * 32 + quad * 8 + 4);
      }
      float ww[8] = {b0.x, b0.y, b0.z, b0.w, b1.x, b1.y, b1.z, b1.w};
#pragma unroll
      for (int j = 0; j < 8; j++){
        unsigned short hi, lo; split_bf(ww[j], hi, lo);
        aqh1[ks][j] = (short)hi; aql1[ks][j] = (short)lo;
      }
    }
  }

  // ---- S = Q K^T / 8 for BOTH tiles, K-fragment reads shared ----
  f32x4 sacc0[13], sacc1[13];
  __builtin_amdgcn_s_setprio(1);
#pragma unroll
  for (int t = 0; t < 13; t++){
    f32x4 a0 = {0.f, 0.f, 0.f, 0.f}, a1 = {0.f, 0.f, 0.f, 0.f};
#pragma unroll
    for (int ks = 0; ks < 2; ks++){
      bf16x8 bkh = *(const bf16x8*)(Khi + (t * 16 + l16) * 72 + ks * 32 + quad * 8);
      bf16x8 bkl = *(const bf16x8*)(Klo + (t * 16 + l16) * 72 + ks * 32 + quad * 8);
      a0 = mfma16(aqh0[ks], bkh, a0);
      a0 = mfma16(aqh0[ks], bkl, a0);
      a0 = mfma16(aql0[ks], bkh, a0);
      if (has2){
        a1 = mfma16(aqh1[ks], bkh, a1);
        a1 = mfma16(aqh1[ks], bkl, a1);
        a1 = mfma16(aql1[ks], bkh, a1);
      }
    }
    sacc0[t] = a0; sacc1[t] = a1;
  }
  __builtin_amdgcn_s_setprio(0);

  // ---- softmax in registers (lane: rows q=quad*4+r, cols s=t*16+l16) ----
  float inv0[4], inv1[4];
  auto softmax_tile = [&](f32x4* sacc, float* inv){
    float mx[4] = {-1e30f, -1e30f, -1e30f, -1e30f};
#pragma unroll
    for (int t = 0; t < 13; t++){
      bool dead = (t == 12) && (l16 >= 4);   // key col >= 196
#pragma unroll
      for (int r = 0; r < 4; r++){
        float v = dead ? -1e30f : sacc[t][r] * 0.125f;
        sacc[t][r] = v;
        mx[r] = fmaxf(mx[r], v);
      }
    }
#pragma unroll
    for (int off = 1; off < 16; off <<= 1)
#pragma unroll
      for (int r = 0; r < 4; r++) mx[r] = fmaxf(mx[r], __shfl_xor(mx[r], off));
    float sum[4] = {0.f, 0.f, 0.f, 0.f};
#pragma unroll
    for (int t = 0; t < 13; t++)
#pragma unroll
      for (int r = 0; r < 4; r++){
        float e = __expf(sacc[t][r] - mx[r]);
        sacc[t][r] = e; sum[r] += e;
      }
#pragma unroll
    for (int off = 1; off < 16; off <<= 1)
#pragma unroll
      for (int r = 0; r < 4; r++) sum[r] += __shfl_xor(sum[r], off);
#pragma unroll
    for (int r = 0; r < 4; r++) inv[r] = 1.0f / sum[r];
  };
  softmax_tile(sacc0, inv0);
  if (has2) softmax_tile(sacc1, inv1);

  // ---- O = P V for BOTH tiles: V-fragment reads shared; Ps scratch time-shared
  // (same-wave DS ops execute in order, so write0->read0->write1->read1 is safe;
  //  wave_barriers stop compiler reordering) ----
  f32x4 oacc0[4] = {}, oacc1[4] = {};
#pragma unroll
  for (int ks = 0; ks < 7; ks++){
    const int t0 = 2 * ks, t1c = 2 * ks + 1;
#pragma unroll
    for (int r = 0; r < 4; r++){
      int row = quad * 4 + r;
      unsigned short hi, lo;
      split_bf(sacc0[t0][r] * inv0[r], hi, lo);
      PsH[row * 40 + l16] = hi; PsL[row * 40 + l16] = lo;
      if (t1c < 13){
        split_bf(sacc0[t1c][r] * inv0[r], hi, lo);
        PsH[row * 40 + 16 + l16] = hi; PsL[row * 40 + 16 + l16] = lo;
      } else {
        PsH[row * 40 + 16 + l16] = 0; PsL[row * 40 + 16 + l16] = 0;
      }
    }
    __builtin_amdgcn_wave_barrier();
    bf16x8 aph0 = *(const bf16x8*)(PsH + l16 * 40 + quad * 8);
    bf16x8 apl0 = *(const bf16x8*)(PsL + l16 * 40 + quad * 8);
    __builtin_amdgcn_wave_barrier();
    bf16x8 aph1 = {}, apl1 = {};
    if (has2){
#pragma unroll
      for (int r = 0; r < 4; r++){
        int row = quad * 4 + r;
        unsigned short hi, lo;
        split_bf(sacc1[t0][r] * inv1[r], hi, lo);
        PsH[row * 40 + l16] = hi; PsL[row * 40 + l16] = lo;
        if (t1c < 13){
          split_bf(sacc1[t1c][r] * inv1[r], hi, lo);
          PsH[row * 40 + 16 + l16] = hi; PsL[row * 40 + 16 + l16] = lo;
        } else {
          PsH[row * 40 + 16 + l16] = 0; PsL[row * 40 + 16 + l16] = 0;
        }
      }
      __builtin_amdgcn_wave_barrier();
      aph1 = *(const bf16x8*)(PsH + l16 * 40 + quad * 8);
      apl1 = *(const bf16x8*)(PsL + l16 * 40 + quad * 8);
      __builtin_amdgcn_wave_barrier();
    }
    __builtin_amdgcn_s_setprio(1);
#pragma unroll
    for (int n = 0; n < 4; n++){
      bf16x8 bvh = *(const bf16x8*)(Vhi + vidx(n * 16 + l16, ks * 32 + quad * 8));
      bf16x8 bvl = *(const bf16x8*)(Vlo + vidx(n * 16 + l16, ks * 32 + quad * 8));
      oacc0[n] = mfma16(aph0, bvh, oacc0[n]);
      oacc0[n] = mfma16(aph0, bvl, oacc0[n]);
      oacc0[n] = mfma16(apl0, bvh, oacc0[n]);
      if (has2){
        oacc1[n] = mfma16(aph1, bvh, oacc1[n]);
        oacc1[n] = mfma16(aph1, bvl, oacc1[n]);
        oacc1[n] = mfma16(apl1, bvh, oacc1[n]);
      }
    }
    __builtin_amdgcn_s_setprio(0);
    __builtin_amdgcn_wave_barrier();   // all reads of this slice done before next-iter writes
  }

  // ---- store ctx (C-layout: row=quad*4+r, col=n*16+l16) + absmax ----
  auto store_tile = [&](int qt, f32x4* oacc){
#pragma unroll
    for (int r = 0; r < 4; r++){
      int srow = qt * 16 + quad * 4 + r;
      if (srow < SEQ){
#pragma unroll
        for (int n = 0; n < 4; n++){
          float v = oacc[n][r];
          ctx[((size_t)(b * SEQ + srow)) * DMODEL + h * 64 + n * 16 + l16] = v;
          gmax = fmaxf(gmax, fabsf(v));
        }
      }
    }
  };
  store_tile(qt0, oacc0);
  if (has2) store_tile(qt1, oacc1);

  for (int off = 32; off; off >>= 1) gmax = fmaxf(gmax, __shfl_xor(gmax, off));
  if (lane == 0) gm8[wv] = gmax;
  __syncthreads();
  if (tid == 0){
    float bm = 0.f;
#pragma unroll
    for (int i = 0; i < 8; i++) bm = fmaxf(bm, gm8[i]);
    scatter_amax(slots, SL_CTX, blockIdx.x, bm);
  }
}

// ---------------- launch ----------------
extern "C" void kernel_launch(void* const* d_in, const int* in_sizes, int n_in,
                              void* d_out, int out_size, void* d_ws, size_t ws_size,
                              hipStream_t stream)
{
  const float* x     = (const float*)d_in[0];
  const float* ln1_g = (const float*)d_in[1];
  const float* ln1_b = (const float*)d_in[2];
  const float* ln2_g = (const float*)d_in[3];
  const float* ln2_b = (const float*)d_in[4];
  const float* w_qkv = (const float*)d_in[5];
  const float* b_qkv = (const float*)d_in[6];
  const float* w_o   = (const float*)d_in[7];
  const float* b_o   = (const float*)d_in[8];
  const float* w1    = (const float*)d_in[9];
  const float* b1    = (const float*)d_in[10];
  const float* w2    = (const float*)d_in[11];
  const float* b2    = (const float*)d_in[12];

  char* ws = (char*)d_ws;
  size_t off = 0;
  unsigned* slots = (unsigned*)ws;                 off += SLOTS_U32 * 4;   // 16 KB scattered slots
  char* wqkvT = (char*)(ws + off); off += (size_t)NQKV  * DMODEL;
  char* woT   = (char*)(ws + off); off += (size_t)DMODEL* DMODEL;
  char* w1T   = (char*)(ws + off); off += (size_t)MMLP  * DMODEL;
  char* w2T   = (char*)(ws + off); off += (size_t)DMODEL* MMLP;
  off = (off + 255) & ~(size_t)255;
  float* t1    = (float*)(ws + off);               off += (size_t)NTOK * DMODEL * 4;
  char*  t1q   = (char*)(ws + off);                off += (size_t)NTOK * DMODEL;
  off = (off + 255) & ~(size_t)255;
  float* qkv   = (float*)(ws + off);               off += (size_t)NTOK * NQKV * 4;
  float* xmid  = (float*)(ws + off);               off += (size_t)NTOK * DMODEL * 4;
  // FC1 bf16 output (77.07 MB) + its int8 quant (38.54 MB) exactly fill the qkv region (115.6 MB)
  unsigned short* h1 = (unsigned short*)qkv;
  char* h1q = (char*)qkv + (size_t)NTOK * MMLP * 2;
  float* outp = (float*)d_out;

  k_init<<<(SLOTS_U32 + 255) / 256, 256, 0, stream>>>(slots);

  k_absmax4<<<896, 256, 0, stream>>>(w_qkv, w_o, w1, w2, slots);

  k_quant_transpose<<<dim3(NQKV / 32, DMODEL / 32), 256, 0, stream>>>(w_qkv, wqkvT, DMODEL, NQKV, slots, SL_WQKV);
  k_quant_transpose<<<dim3(DMODEL / 32, DMODEL / 32), 256, 0, stream>>>(w_o, woT, DMODEL, DMODEL, slots, SL_WO);
  k_quant_transpose<<<dim3(MMLP / 32, DMODEL / 32), 256, 0, stream>>>(w1, w1T, DMODEL, MMLP, slots, SL_W1);
  k_quant_transpose<<<dim3(DMODEL / 32, MMLP / 32), 256, 0, stream>>>(w2, w2T, MMLP, DMODEL, slots, SL_W2);

  // LN1 -> quant -> QKV
  k_layernorm<<<NTOK / 4, 256, 0, stream>>>(x, ln1_g, ln1_b, t1, slots, SL_LN1);
  {
    int n4 = NTOK * DMODEL / 4;
    k_quant_act<<<(n4 + 255) / 256, 256, 0, stream>>>(t1, (unsigned*)t1q, n4, slots, SL_LN1);
  }
  k_gemm<0><<<dim3(NQKV / 128, NTOK / 128), 256, 0, stream>>>(
      t1q, wqkvT, b_qkv, nullptr, qkv, nullptr, slots, SL_LN1, SL_WQKV, nullptr, 0,
      NTOK, NQKV, DMODEL);

  // attention -> ctx (t1) + absmax
  k_attention<<<NBATCH * NHEAD, 512, 0, stream>>>(qkv, t1, slots);
  {
    int n4 = NTOK * DMODEL / 4;
    k_quant_act<<<(n4 + 255) / 256, 256, 0, stream>>>(t1, (unsigned*)t1q, n4, slots, SL_CTX);
  }
  // O-proj + residual -> xmid
  k_gemm<1><<<dim3(DMODEL / 128, NTOK / 128), 256, 0, stream>>>(
      t1q, woT, b_o, x, xmid, nullptr, slots, SL_CTX, SL_WO, nullptr, 0,
      NTOK, DMODEL, DMODEL);

  // LN2 -> quant -> FC1(+gelu->bf16) -> quant -> FC2 + residual -> out
  k_layernorm<<<NTOK / 4, 256, 0, stream>>>(xmid, ln2_g, ln2_b, t1, slots, SL_LN2);
  {
    int n4 = NTOK * DMODEL / 4;
    k_quant_act<<<(n4 + 255) / 256, 256, 0, stream>>>(t1, (unsigned*)t1q, n4, slots, SL_LN2);
  }
  k_gemm<2><<<dim3(MMLP / 128, NTOK / 128), 256, 0, stream>>>(
      t1q, w1T, b1, nullptr, nullptr, h1, slots, SL_LN2, SL_W1, slots, SL_GELU,
      NTOK, MMLP, DMODEL);
  {
    int n4 = NTOK * MMLP / 4;
    k_quant_bf16_i8<<<(n4 + 255) / 256, 256, 0, stream>>>(h1, (unsigned*)h1q, n4, slots, SL_GELU);
  }
  k_gemm<1><<<dim3(DMODEL / 128, NTOK / 128), 256, 0, stream>>>(
      h1q, w2T, b2, xmid, outp, nullptr, slots, SL_GELU, SL_W2, nullptr, 0,
      NTOK, DMODEL, MMLP);
}

// Round 5
// 468.000 us; speedup vs baseline: 1.0855x; 1.0855x over previous
//
#include <hip/hip_runtime.h>
#include <cstdint>
#include <cstddef>

#define DEVFN __device__ __forceinline__

typedef short bf16x8 __attribute__((ext_vector_type(8)));
typedef float f32x4  __attribute__((ext_vector_type(4)));
typedef int   i32x4  __attribute__((ext_vector_type(4)));

// problem constants
static constexpr int NTOK  = 64 * 196;   // 12544  (= 98 * 128)
static constexpr int DMODEL= 768;
static constexpr int NHEAD = 12;
static constexpr int NQKV  = 2304;       // 3*768 (= 18 * 128)
static constexpr int MMLP  = 3072;       // 4*768 (= 24 * 128)
static constexpr int SEQ   = 196;
static constexpr int NBATCH= 64;

// scale slots (absmax bits, atomicMax on uint reinterpretation of fp32)
enum { SL_LN1=0, SL_WQKV=1, SL_CTX=2, SL_WO=3, SL_LN2=4, SL_W1=5, SL_GELU=6, SL_W2=7 };

// ---- scattered absmax slots: 64 shadow copies per logical slot, 256B apart ----
static constexpr int NSH       = 64;     // shadow buckets per slot
static constexpr int SH_STRIDE = 64;     // uints between buckets (256 B lines)
static constexpr int SLOTS_U32 = NSH * SH_STRIDE;   // 4096 uints = 16 KB

DEVFN float bf2f(unsigned short u){ return __uint_as_float(((unsigned)u) << 16); }
DEVFN unsigned short f2bf(float f){            // round-to-nearest-even
  unsigned u = __float_as_uint(f);
  u += 0x7fffu + ((u >> 16) & 1u);
  return (unsigned short)(u >> 16);
}
DEVFN void split_bf(float v, unsigned short& hi, unsigned short& lo){
  hi = f2bf(v);
  lo = f2bf(v - bf2f(hi));                     // v-hi is exact in fp32
}
DEVFN float slot_absmax(const unsigned* __restrict__ slots, int slot){
  unsigned m = 0u;
#pragma unroll
  for (int j = 0; j < NSH; j++){
    unsigned u = slots[j * SH_STRIDE + slot];  // uniform scalar loads, L2-hot
    m = (u > m) ? u : m;                       // bits >=0: uint order == float order
  }
  return __uint_as_float(m);
}
DEVFN float slot_scale(const unsigned* __restrict__ slots, int slot){
  return fmaxf(slot_absmax(slots, slot) / 127.0f, 1e-8f);   // exact match to ref: max/127.0
}
DEVFN void scatter_amax(unsigned* slots, int slot, unsigned bucket, float v){
  atomicMax(slots + (bucket & (NSH - 1)) * SH_STRIDE + slot, __float_as_uint(v));
}
DEVFN float quantval(float x, float s){        // integer-valued quantized result
  float q = rintf(x / s);                      // RNE, matches jnp.round
  return fminf(fmaxf(q, -128.0f), 127.0f);
}
DEVFN unsigned pack4(float a, float b, float c, float d){
  return  ((unsigned)(unsigned char)(char)(int)a)
        | ((unsigned)(unsigned char)(char)(int)b << 8)
        | ((unsigned)(unsigned char)(char)(int)c << 16)
        | ((unsigned)(unsigned char)(char)(int)d << 24);
}
// exact-GELU with branch-free A&S 7.1.26 erf (max abs err 1.5e-7, invisible
// under the immediate bf16 rounding of the result).
DEVFN float gelu_fast(float v){
  float s  = v * 0.70710678118654752f;
  float ax = fabsf(s);
  float t  = __builtin_amdgcn_rcpf(fmaf(0.3275911f, ax, 1.0f));
  float p  = t * fmaf(t, fmaf(t, fmaf(t, fmaf(t, 1.061405429f, -1.453152027f),
                                      1.421413741f), -0.284496736f), 0.254829592f);
  float er = fmaf(-p, __expf(-ax * ax), 1.0f);           // erf(|s|) in [0,1)
  unsigned sgn = __float_as_uint(s) & 0x80000000u;
  er = __uint_as_float(__float_as_uint(er) | sgn);
  return 0.5f * v * (1.0f + er);
}
DEVFN f32x4 mfma16(bf16x8 a, bf16x8 b, f32x4 c){
  return __builtin_amdgcn_mfma_f32_16x16x32_bf16(a, b, c, 0, 0, 0);
}
DEVFN i32x4 mfma16i8(i32x4 a, i32x4 b, i32x4 c){
  return __builtin_amdgcn_mfma_i32_16x16x64_i8(a, b, c, 0, 0, 0);
}
DEVFN void async_ld16(const void* g, void* lds){
  __builtin_amdgcn_global_load_lds((const __attribute__((address_space(1))) void*)g,
                                   (__attribute__((address_space(3))) void*)lds, 16, 0, 0);
}
// V^T LDS layout: stride 256 ushorts + XOR swizzle on s-bits 3..5.
DEVFN int vidx(int d, int s){
  return d * 256 + (s ^ (((d ^ (d >> 2)) & 7) << 3));
}

// ---------------- init scale slots ----------------
__global__ void k_init(unsigned* slots){
  int i = blockIdx.x * blockDim.x + threadIdx.x;
  if (i < SLOTS_U32) slots[i] = 0u;
}

// ---------------- fused absmax of the 4 weight tensors (1 launch) ----------------
__global__ void k_absmax4(const float* __restrict__ x0, const float* __restrict__ x1,
                          const float* __restrict__ x2, const float* __restrict__ x3,
                          unsigned* slots){
  int bid = blockIdx.x;
  const float* x; int n4, slot, b0, nb;
  if (bid < 256)      { x = x0; n4 = DMODEL * NQKV  / 4; slot = SL_WQKV; b0 = 0;   nb = 256; }
  else if (bid < 384) { x = x1; n4 = DMODEL * DMODEL/ 4; slot = SL_WO;   b0 = 256; nb = 128; }
  else if (bid < 640) { x = x2; n4 = DMODEL * MMLP  / 4; slot = SL_W1;   b0 = 384; nb = 256; }
  else                { x = x3; n4 = MMLP   * DMODEL/ 4; slot = SL_W2;   b0 = 640; nb = 256; }
  int lb = bid - b0;
  float m = 0.f;
  const float4* x4 = (const float4*)x;
  int stride = nb * blockDim.x;
  for (int j = lb * blockDim.x + threadIdx.x; j < n4; j += stride){
    float4 v = x4[j];
    m = fmaxf(m, fmaxf(fmaxf(fabsf(v.x), fabsf(v.y)), fmaxf(fabsf(v.z), fabsf(v.w))));
  }
  for (int off = 32; off; off >>= 1) m = fmaxf(m, __shfl_xor(m, off));
  __shared__ float wm[4];
  int lane = threadIdx.x & 63, w = threadIdx.x >> 6;
  if (lane == 0) wm[w] = m;
  __syncthreads();
  if (threadIdx.x == 0){
    float bm = fmaxf(fmaxf(wm[0], wm[1]), fmaxf(wm[2], wm[3]));
    scatter_amax(slots, slot, bid, bm);
  }
}

// ---------------- quantize 4 weights (K x N fp32) -> transposed int8 (N x K), 1 launch --------
__global__ void k_quant_transpose4(const float* __restrict__ w0, const float* __restrict__ w1,
                                   const float* __restrict__ w2, const float* __restrict__ w3,
                                   char* __restrict__ t0, char* __restrict__ t1,
                                   char* __restrict__ t2, char* __restrict__ t3,
                                   const unsigned* __restrict__ slots){
  // seg tile counts: qkv 72x24=1728 | wo 24x24=576 | w1 96x24=2304 | w2 24x96=2304
  int bid = blockIdx.x;
  const float* w; char* wt; int K, N, slot, lb;
  if (bid < 1728)      { w = w0; wt = t0; K = DMODEL; N = NQKV;   slot = SL_WQKV; lb = bid; }
  else if (bid < 2304) { w = w1; wt = t1; K = DMODEL; N = DMODEL; slot = SL_WO;   lb = bid - 1728; }
  else if (bid < 4608) { w = w2; wt = t2; K = DMODEL; N = MMLP;   slot = SL_W1;   lb = bid - 2304; }
  else                 { w = w3; wt = t3; K = MMLP;   N = DMODEL; slot = SL_W2;   lb = bid - 4608; }
  int nx = N / 32;
  int bx = lb % nx, by = lb / nx;

  __shared__ float tile[32][33];
  float s = slot_scale(slots, slot);
  int n0 = bx * 32, k0 = by * 32;
  int tx = threadIdx.x & 31, ty = threadIdx.x >> 5;   // 256 threads: ty 0..7
#pragma unroll
  for (int i = 0; i < 4; i++){
    int k = k0 + ty + i * 8;
    float v = w[(size_t)k * N + n0 + tx];
    tile[ty + i * 8][tx] = quantval(v, s);
  }
  __syncthreads();
  int n = threadIdx.x >> 3, kg = threadIdx.x & 7;
  unsigned o = pack4(tile[kg * 4 + 0][n], tile[kg * 4 + 1][n],
                     tile[kg * 4 + 2][n], tile[kg * 4 + 3][n]);
  *(unsigned*)(wt + (size_t)(n0 + n) * K + k0 + kg * 4) = o;
}

// ---------------- layernorm (rows of 768) + absmax ----------------
__global__ void k_layernorm(const float* __restrict__ x, const float* __restrict__ g,
                            const float* __restrict__ b, float* __restrict__ out,
                            unsigned* slots, int slot){
  int w = threadIdx.x >> 6, lane = threadIdx.x & 63;
  int row = blockIdx.x * 4 + w;
  const float4* xr = (const float4*)(x + (size_t)row * DMODEL);
  float4 v[3];
  float sum = 0.f;
#pragma unroll
  for (int i = 0; i < 3; i++){ v[i] = xr[i * 64 + lane]; sum += v[i].x + v[i].y + v[i].z + v[i].w; }
  for (int off = 32; off; off >>= 1) sum += __shfl_xor(sum, off);
  float mu = sum * (1.0f / 768.0f);
  float vs = 0.f;
#pragma unroll
  for (int i = 0; i < 3; i++){
    float dx = v[i].x - mu, dy = v[i].y - mu, dz = v[i].z - mu, dw = v[i].w - mu;
    vs += dx * dx + dy * dy + dz * dz + dw * dw;
  }
  for (int off = 32; off; off >>= 1) vs += __shfl_xor(vs, off);
  float inv = 1.0f / sqrtf(vs * (1.0f / 768.0f) + 1e-5f);
  const float4* g4 = (const float4*)g; const float4* b4 = (const float4*)b;
  float4* o4 = (float4*)(out + (size_t)row * DMODEL);
  float am = 0.f;
#pragma unroll
  for (int i = 0; i < 3; i++){
    float4 gg = g4[i * 64 + lane], bb = b4[i * 64 + lane], o;
    o.x = (v[i].x - mu) * inv * gg.x + bb.x;
    o.y = (v[i].y - mu) * inv * gg.y + bb.y;
    o.z = (v[i].z - mu) * inv * gg.z + bb.z;
    o.w = (v[i].w - mu) * inv * gg.w + bb.w;
    am = fmaxf(am, fmaxf(fmaxf(fabsf(o.x), fabsf(o.y)), fmaxf(fabsf(o.z), fabsf(o.w))));
    o4[i * 64 + lane] = o;
  }
  for (int off = 32; off; off >>= 1) am = fmaxf(am, __shfl_xor(am, off));
  __shared__ float am4[4];
  if (lane == 0) am4[w] = am;
  __syncthreads();
  if (threadIdx.x == 0){
    float bm = fmaxf(fmaxf(am4[0], am4[1]), fmaxf(am4[2], am4[3]));
    scatter_amax(slots, slot, blockIdx.x, bm);
  }
}

// ---------------- quantize fp32 activations -> packed int8 ----------------
__global__ void k_quant_act(const float* __restrict__ x, unsigned* __restrict__ out,
                            int n4, const unsigned* __restrict__ slots, int slot){
  float s = slot_scale(slots, slot);
  const float4* x4 = (const float4*)x;
  int stride = gridDim.x * blockDim.x;
  for (int j = blockIdx.x * blockDim.x + threadIdx.x; j < n4; j += stride){
    float4 v = x4[j];
    out[j] = pack4(quantval(v.x, s), quantval(v.y, s), quantval(v.z, s), quantval(v.w, s));
  }
}

// ---------------- quantize bf16 activations -> packed int8 ----------------
__global__ void k_quant_bf16_i8(const unsigned short* __restrict__ x, unsigned* __restrict__ out,
                                int n4, const unsigned* __restrict__ slots, int slot){
  float s = slot_scale(slots, slot);
  const ushort4* x4 = (const ushort4*)x;
  int stride = gridDim.x * blockDim.x;
  for (int j = blockIdx.x * blockDim.x + threadIdx.x; j < n4; j += stride){
    ushort4 v = x4[j];
    out[j] = pack4(quantval(bf2f(v.x), s), quantval(bf2f(v.y), s),
                   quantval(bf2f(v.z), s), quantval(bf2f(v.w), s));
  }
}

// ---------------- int8 GEMM: C[M,N] = sa*sb * (A[M,K] @ Bt[N,K]^T) + bias (+res / gelu) ---------
template<int EPI>
__launch_bounds__(256, 4)
__global__ void k_gemm(const char* __restrict__ A,    // M x K int8
                       const char* __restrict__ Bt,   // N x K int8
                       const float* __restrict__ bias,
                       const float* __restrict__ res,
                       float* __restrict__ Cf,
                       unsigned short* __restrict__ Cb,
                       const unsigned* __restrict__ slots, int sa_slot, int sb_slot,
                       unsigned* gmax_slots, int gmax_slot,
                       int M, int N, int K)
{
  __shared__ __align__(16) char smem[32768];
  __shared__ float gm4[4];
  const int tid  = threadIdx.x;
  const int lane = tid & 63;
  const int wv   = tid >> 6;        // 0..3
  const int wx   = wv & 1, wy = wv >> 1;
  const int quad = lane >> 4;
  const int l16  = lane & 15;
  const int m0 = blockIdx.y * 128, n0 = blockIdx.x * 128;

  auto issue = [&](int k0, int buf){
#pragma unroll
    for (int i = 0; i < 2; i++){     // A tile: 512 chunks of 16B (row = c>>2, q = c&3)
      int c = tid + i * 256;
      int row = c >> 2, q = c & 3;
      int qs = (q - ((row + (row >> 2)) & 3)) & 3;   // inverse chunk rotation
      async_ld16(A + (size_t)(m0 + row) * K + k0 + qs * 16,
                 smem + buf * 8192 + (i * 256 + wv * 64) * 16);
    }
#pragma unroll
    for (int i = 0; i < 2; i++){     // B tile
      int c = tid + i * 256;
      int row = c >> 2, q = c & 3;
      int qs = (q - ((row + (row >> 2)) & 3)) & 3;
      async_ld16(Bt + (size_t)(n0 + row) * K + k0 + qs * 16,
                 smem + 16384 + buf * 8192 + (i * 256 + wv * 64) * 16);
    }
  };

  i32x4 acc[4][4] = {};
  const int nk = K >> 6;
  issue(0, 0);

  const int ch = (((quad + (l16 & 3) + (l16 >> 2)) & 3)) * 16;

  for (int k = 0; k < nk; k++){
    const int cur = k & 1;
    if (k + 1 < nk){
      issue((k + 1) << 6, cur ^ 1);                       // prefetch next tile
      asm volatile("s_waitcnt vmcnt(4)" ::: "memory");    // tile-k loads landed; k+1 in flight
    } else {
      asm volatile("s_waitcnt vmcnt(0)" ::: "memory");
    }
    asm volatile("s_barrier" ::: "memory");               // tile-k visible to all waves

    const char* Ab = smem + cur * 8192;
    const char* Bb = smem + 16384 + cur * 8192;
    i32x4 af[4], bfr[4];
#pragma unroll
    for (int i = 0; i < 4; i++)
      af[i] = *(const i32x4*)(Ab + (wy * 64 + i * 16 + l16) * 64 + ch);
#pragma unroll
    for (int j = 0; j < 4; j++)
      bfr[j] = *(const i32x4*)(Bb + (wx * 64 + j * 16 + l16) * 64 + ch);
    asm volatile("s_waitcnt lgkmcnt(0)" ::: "memory");    // frags in regs
    asm volatile("s_barrier" ::: "memory");               // all reads of cur done

#pragma unroll
    for (int i = 0; i < 4; i++)
#pragma unroll
      for (int j = 0; j < 4; j++)
        acc[i][j] = mfma16i8(af[i], bfr[j], acc[i][j]);
  }
  __syncthreads();   // all waves out of the K-loop before stage overlay is used

  // ---- epilogue: 4 slices of 32 rows; LDS transpose -> coalesced wide loads/stores ----
  float (*stage)[132] = (float (*)[132])smem;   // 16896 B, overlays dead tile buffers
  const float sc = slot_scale(slots, sa_slot) * slot_scale(slots, sb_slot);
  const int col4 = (tid & 31) * 4;           // 0..124
  const int gc   = n0 + col4;
  const float4 bb = *(const float4*)&bias[gc];
  float gmax = 0.f;
#pragma unroll
  for (int i = 0; i < 4; i++){
#pragma unroll
    for (int j = 0; j < 4; j++)
#pragma unroll
      for (int r = 0; r < 4; r++)
        stage[wy * 16 + quad * 4 + r][wx * 64 + j * 16 + l16] = (float)acc[i][j][r];
    __syncthreads();
#pragma unroll
    for (int rr = 0; rr < 4; rr++){
      const int rl = rr * 8 + (tid >> 5);                       // 0..31
      const int gm = m0 + ((rl >> 4) * 64) + i * 16 + (rl & 15);
      float4 v = *(const float4*)&stage[rl][col4];
      v.x = v.x * sc + bb.x; v.y = v.y * sc + bb.y;
      v.z = v.z * sc + bb.z; v.w = v.w * sc + bb.w;
      if constexpr (EPI == 1){
        float4 rv = *(const float4*)&res[(size_t)gm * N + gc];
        v.x += rv.x; v.y += rv.y; v.z += rv.z; v.w += rv.w;
        *(float4*)&Cf[(size_t)gm * N + gc] = v;
      } else if constexpr (EPI == 2){
        float g0 = gelu_fast(v.x);
        float g1 = gelu_fast(v.y);
        float g2 = gelu_fast(v.z);
        float g3 = gelu_fast(v.w);
        gmax = fmaxf(gmax, fmaxf(fmaxf(fabsf(g0), fabsf(g1)), fmaxf(fabsf(g2), fabsf(g3))));
        ushort4 o = {f2bf(g0), f2bf(g1), f2bf(g2), f2bf(g3)};
        *(ushort4*)&Cb[(size_t)gm * N + gc] = o;
      } else {
        *(float4*)&Cf[(size_t)gm * N + gc] = v;
      }
    }
    __syncthreads();
  }
  if constexpr (EPI == 2){
    for (int off = 32; off; off >>= 1) gmax = fmaxf(gmax, __shfl_xor(gmax, off));
    if (lane == 0) gm4[wv] = gmax;
    __syncthreads();
    if (tid == 0){
      float bm = fmaxf(fmaxf(gm4[0], gm4[1]), fmaxf(gm4[2], gm4[3]));
      scatter_amax(gmax_slots, gmax_slot, blockIdx.x + blockIdx.y * gridDim.x, bm);
    }
  }
}

// ---------------- attention: one block per (b,h), 13 waves, ONE q-tile per wave ----------------
// 832 threads = 13 waves; wave w owns q-tile w. Critical path = one tile-pass (was two for
// 5 of 8 waves), wave imbalance eliminated, 13 waves hide latency (was 8).
__launch_bounds__(832, 4)
__global__ void k_attention(const float* __restrict__ qkv, float* __restrict__ ctx,
                            unsigned* slots){
  __shared__ __align__(16) unsigned short Khi[208 * 72], Klo[208 * 72];   // 59,904 B
  __shared__ __align__(16) unsigned short Vhi[64 * 256], Vlo[64 * 256];   // 65,536 B (swizzled)
  __shared__ __align__(16) unsigned short Ps[13][2][16 * 40];             // 33,280 B (per-wave hi/lo)
  __shared__ float gm[13];

  const int bh = blockIdx.x;
  const int b = bh / NHEAD, h = bh % NHEAD;
  const float* base = qkv + (size_t)b * SEQ * NQKV;
  const int tid = threadIdx.x, lane = tid & 63, wv = tid >> 6;   // wv 0..12
  const int quad = lane >> 4, l16 = lane & 15;

  // ---- prefetch ALL K/V global data into registers, then convert+write LDS ----
  float4 kreg[4], vreg[5];
#pragma unroll
  for (int i = 0; i < 4; i++){
    int idx = tid + i * 832;                  // K: 208*16 = 3328 chunks (4*832 exact)
    int r = idx >> 4, c4 = (idx & 15) * 4;
    float4 v = {0.f, 0.f, 0.f, 0.f};
    if (r < SEQ) v = *(const float4*)(base + (size_t)r * NQKV + DMODEL + h * 64 + c4);
    kreg[i] = v;
  }
#pragma unroll
  for (int i = 0; i < 5; i++){
    int idx = tid + i * 832;                  // V: 232*16 = 3712 chunks (incl. zero pad)
    int s = idx >> 4, dg = (idx & 15) * 4;
    float4 v = {0.f, 0.f, 0.f, 0.f};
    if (idx < 232 * 16 && s < SEQ)
      v = *(const float4*)(base + (size_t)s * NQKV + 2 * DMODEL + h * 64 + dg);
    vreg[i] = v;
  }
#pragma unroll
  for (int i = 0; i < 4; i++){
    int idx = tid + i * 832;
    int r = idx >> 4, c4 = (idx & 15) * 4;
    float4 v = kreg[i];
    unsigned short h0,l0,h1,l1,h2,l2,h3,l3;
    split_bf(v.x, h0, l0); split_bf(v.y, h1, l1); split_bf(v.z, h2, l2); split_bf(v.w, h3, l3);
    ushort4 hs = {h0, h1, h2, h3}, ls = {l0, l1, l2, l3};
    *(ushort4*)(Khi + r * 72 + c4) = hs;
    *(ushort4*)(Klo + r * 72 + c4) = ls;
  }
#pragma unroll
  for (int i = 0; i < 5; i++){
    int idx = tid + i * 832;
    if (idx < 232 * 16){
      int s = idx >> 4, dg = (idx & 15) * 4;
      float4 v = vreg[i];
      unsigned short hi, lo;
      split_bf(v.x, hi, lo); Vhi[vidx(dg + 0, s)] = hi; Vlo[vidx(dg + 0, s)] = lo;
      split_bf(v.y, hi, lo); Vhi[vidx(dg + 1, s)] = hi; Vlo[vidx(dg + 1, s)] = lo;
      split_bf(v.z, hi, lo); Vhi[vidx(dg + 2, s)] = hi; Vlo[vidx(dg + 2, s)] = lo;
      split_bf(v.w, hi, lo); Vhi[vidx(dg + 3, s)] = hi; Vlo[vidx(dg + 3, s)] = lo;
    }
  }
  __syncthreads();    // the ONLY full-block barrier in the main body

  unsigned short* PsH = &Ps[wv][0][0];
  unsigned short* PsL = &Ps[wv][1][0];

  float gmax = 0.f;
  const int qt = wv;                 // one q-tile per wave
  {
    const int q0 = qt * 16;
    const int sq = q0 + l16;
    const bool valid = sq < SEQ;

    // Q fragments straight from global (A-layout: m=l16, k=quad*8+j), split hi/lo
    bf16x8 aqh[2], aql[2];
    const float* qrow = base + (size_t)(valid ? sq : 0) * NQKV + h * 64;
#pragma unroll
    for (int ks = 0; ks < 2; ks++){
      float4 v0 = {0,0,0,0}, v1 = {0,0,0,0};
      if (valid){
        v0 = *(const float4*)(qrow + ks * 32 + quad * 8);
        v1 = *(const float4*)(qrow + ks * 32 + quad * 8 + 4);
      }
      float vv[8] = {v0.x, v0.y, v0.z, v0.w, v1.x, v1.y, v1.z, v1.w};
#pragma unroll
      for (int j = 0; j < 8; j++){
        unsigned short hi, lo; split_bf(vv[j], hi, lo);
        aqh[ks][j] = (short)hi; aql[ks][j] = (short)lo;
      }
    }

    // ---- S = Q K^T / 8 : 13 independent MFMA chains ----
    f32x4 sacc[13];
    __builtin_amdgcn_s_setprio(1);
#pragma unroll
    for (int t = 0; t < 13; t++){
      f32x4 a = {0.f, 0.f, 0.f, 0.f};
#pragma unroll
      for (int ks = 0; ks < 2; ks++){
        bf16x8 bkh = *(const bf16x8*)(Khi + (t * 16 + l16) * 72 + ks * 32 + quad * 8);
        bf16x8 bkl = *(const bf16x8*)(Klo + (t * 16 + l16) * 72 + ks * 32 + quad * 8);
        a = mfma16(aqh[ks], bkh, a);
        a = mfma16(aqh[ks], bkl, a);
        a = mfma16(aql[ks], bkh, a);
      }
      sacc[t] = a;
    }
    __builtin_amdgcn_s_setprio(0);

    // ---- softmax in registers: lane holds rows q=quad*4+r, cols s=t*16+l16 ----
    float mx[4] = {-1e30f, -1e30f, -1e30f, -1e30f};
#pragma unroll
    for (int t = 0; t < 13; t++){
      bool dead = (t == 12) && (l16 >= 4);   // key col >= 196
#pragma unroll
      for (int r = 0; r < 4; r++){
        float v = dead ? -1e30f : sacc[t][r] * 0.125f;
        sacc[t][r] = v;
        mx[r] = fmaxf(mx[r], v);
      }
    }
#pragma unroll
    for (int off = 1; off < 16; off <<= 1)
#pragma unroll
      for (int r = 0; r < 4; r++) mx[r] = fmaxf(mx[r], __shfl_xor(mx[r], off));
    float sum[4] = {0.f, 0.f, 0.f, 0.f};
#pragma unroll
    for (int t = 0; t < 13; t++)
#pragma unroll
      for (int r = 0; r < 4; r++){
        float e = __expf(sacc[t][r] - mx[r]);
        sacc[t][r] = e; sum[r] += e;
      }
#pragma unroll
    for (int off = 1; off < 16; off <<= 1)
#pragma unroll
      for (int r = 0; r < 4; r++) sum[r] += __shfl_xor(sum[r], off);
    float inv[4];
#pragma unroll
    for (int r = 0; r < 4; r++) inv[r] = 1.0f / sum[r];

    // ---- O = P V : per-ks transpose C->A layout through per-wave scratch, no barrier ----
    f32x4 oacc[4] = {};
#pragma unroll
    for (int ks = 0; ks < 7; ks++){
      const int t0 = 2 * ks, t1 = 2 * ks + 1;
#pragma unroll
      for (int r = 0; r < 4; r++){
        int row = quad * 4 + r;
        unsigned short hi, lo;
        split_bf(sacc[t0][r] * inv[r], hi, lo);
        PsH[row * 40 + l16] = hi; PsL[row * 40 + l16] = lo;
        if (t1 < 13){
          split_bf(sacc[t1][r] * inv[r], hi, lo);
          PsH[row * 40 + 16 + l16] = hi; PsL[row * 40 + 16 + l16] = lo;
        } else {
          PsH[row * 40 + 16 + l16] = 0; PsL[row * 40 + 16 + l16] = 0;
        }
      }
      __builtin_amdgcn_wave_barrier();   // keep compiler from reordering the RAW through LDS
      bf16x8 aph = *(const bf16x8*)(PsH + l16 * 40 + quad * 8);
      bf16x8 apl = *(const bf16x8*)(PsL + l16 * 40 + quad * 8);
      __builtin_amdgcn_s_setprio(1);
#pragma unroll
      for (int n = 0; n < 4; n++){
        bf16x8 bvh = *(const bf16x8*)(Vhi + vidx(n * 16 + l16, ks * 32 + quad * 8));
        bf16x8 bvl = *(const bf16x8*)(Vlo + vidx(n * 16 + l16, ks * 32 + quad * 8));
        oacc[n] = mfma16(aph, bvh, oacc[n]);
        oacc[n] = mfma16(aph, bvl, oacc[n]);
        oacc[n] = mfma16(apl, bvh, oacc[n]);
      }
      __builtin_amdgcn_s_setprio(0);
      __builtin_amdgcn_wave_barrier();   // reads of this slice complete before next-iter writes
    }

    // ---- store ctx (C-layout: row=quad*4+r, col=n*16+l16) + absmax ----
#pragma unroll
    for (int r = 0; r < 4; r++){
      int srow = q0 + quad * 4 + r;
      if (srow < SEQ){
#pragma unroll
        for (int n = 0; n < 4; n++){
          float v = oacc[n][r];
          ctx[((size_t)(b * SEQ + srow)) * DMODEL + h * 64 + n * 16 + l16] = v;
          gmax = fmaxf(gmax, fabsf(v));
        }
      }
    }
  }
  for (int off = 32; off; off >>= 1) gmax = fmaxf(gmax, __shfl_xor(gmax, off));
  if (lane == 0) gm[wv] = gmax;
  __syncthreads();
  if (tid == 0){
    float bm = 0.f;
#pragma unroll
    for (int i = 0; i < 13; i++) bm = fmaxf(bm, gm[i]);
    scatter_amax(slots, SL_CTX, blockIdx.x, bm);
  }
}

// ---------------- launch ----------------
extern "C" void kernel_launch(void* const* d_in, const int* in_sizes, int n_in,
                              void* d_out, int out_size, void* d_ws, size_t ws_size,
                              hipStream_t stream)
{
  const float* x     = (const float*)d_in[0];
  const float* ln1_g = (const float*)d_in[1];
  const float* ln1_b = (const float*)d_in[2];
  const float* ln2_g = (const float*)d_in[3];
  const float* ln2_b = (const float*)d_in[4];
  const float* w_qkv = (const float*)d_in[5];
  const float* b_qkv = (const float*)d_in[6];
  const float* w_o   = (const float*)d_in[7];
  const float* b_o   = (const float*)d_in[8];
  const float* w1    = (const float*)d_in[9];
  const float* b1    = (const float*)d_in[10];
  const float* w2    = (const float*)d_in[11];
  const float* b2    = (const float*)d_in[12];

  char* ws = (char*)d_ws;
  size_t off = 0;
  unsigned* slots = (unsigned*)ws;                 off += SLOTS_U32 * 4;   // 16 KB scattered slots
  char* wqkvT = (char*)(ws + off); off += (size_t)NQKV  * DMODEL;
  char* woT   = (char*)(ws + off); off += (size_t)DMODEL* DMODEL;
  char* w1T   = (char*)(ws + off); off += (size_t)MMLP  * DMODEL;
  char* w2T   = (char*)(ws + off); off += (size_t)DMODEL* MMLP;
  off = (off + 255) & ~(size_t)255;
  float* t1    = (float*)(ws + off);               off += (size_t)NTOK * DMODEL * 4;
  char*  t1q   = (char*)(ws + off);                off += (size_t)NTOK * DMODEL;
  off = (off + 255) & ~(size_t)255;
  float* qkv   = (float*)(ws + off);               off += (size_t)NTOK * NQKV * 4;
  float* xmid  = (float*)(ws + off);               off += (size_t)NTOK * DMODEL * 4;
  // FC1 bf16 output (77.07 MB) + its int8 quant (38.54 MB) exactly fill the qkv region (115.6 MB)
  unsigned short* h1 = (unsigned short*)qkv;
  char* h1q = (char*)qkv + (size_t)NTOK * MMLP * 2;
  float* outp = (float*)d_out;

  k_init<<<(SLOTS_U32 + 255) / 256, 256, 0, stream>>>(slots);

  k_absmax4<<<896, 256, 0, stream>>>(w_qkv, w_o, w1, w2, slots);

  k_quant_transpose4<<<6912, 256, 0, stream>>>(w_qkv, w_o, w1, w2,
                                               wqkvT, woT, w1T, w2T, slots);

  // LN1 -> quant -> QKV
  k_layernorm<<<NTOK / 4, 256, 0, stream>>>(x, ln1_g, ln1_b, t1, slots, SL_LN1);
  {
    int n4 = NTOK * DMODEL / 4;
    k_quant_act<<<2048, 256, 0, stream>>>(t1, (unsigned*)t1q, n4, slots, SL_LN1);
  }
  k_gemm<0><<<dim3(NQKV / 128, NTOK / 128), 256, 0, stream>>>(
      t1q, wqkvT, b_qkv, nullptr, qkv, nullptr, slots, SL_LN1, SL_WQKV, nullptr, 0,
      NTOK, NQKV, DMODEL);

  // attention -> ctx (t1) + absmax
  k_attention<<<NBATCH * NHEAD, 832, 0, stream>>>(qkv, t1, slots);
  {
    int n4 = NTOK * DMODEL / 4;
    k_quant_act<<<2048, 256, 0, stream>>>(t1, (unsigned*)t1q, n4, slots, SL_CTX);
  }
  // O-proj + residual -> xmid
  k_gemm<1><<<dim3(DMODEL / 128, NTOK / 128), 256, 0, stream>>>(
      t1q, woT, b_o, x, xmid, nullptr, slots, SL_CTX, SL_WO, nullptr, 0,
      NTOK, DMODEL, DMODEL);

  // LN2 -> quant -> FC1(+gelu->bf16) -> quant -> FC2 + residual -> out
  k_layernorm<<<NTOK / 4, 256, 0, stream>>>(xmid, ln2_g, ln2_b, t1, slots, SL_LN2);
  {
    int n4 = NTOK * DMODEL / 4;
    k_quant_act<<<2048, 256, 0, stream>>>(t1, (unsigned*)t1q, n4, slots, SL_LN2);
  }
  k_gemm<2><<<dim3(MMLP / 128, NTOK / 128), 256, 0, stream>>>(
      t1q, w1T, b1, nullptr, nullptr, h1, slots, SL_LN2, SL_W1, slots, SL_GELU,
      NTOK, MMLP, DMODEL);
  {
    int n4 = NTOK * MMLP / 4;
    k_quant_bf16_i8<<<2048, 256, 0, stream>>>(h1, (unsigned*)h1q, n4, slots, SL_GELU);
  }
  k_gemm<1><<<dim3(DMODEL / 128, NTOK / 128), 256, 0, stream>>>(
      h1q, w2T, b2, xmid, outp, nullptr, slots, SL_GELU, SL_W2, nullptr, 0,
      NTOK, DMODEL, MMLP);
}

// Round 7
// 443.492 us; speedup vs baseline: 1.1455x; 1.0553x over previous
//
#include <hip/hip_runtime.h>
#include <cstdint>
#include <cstddef>

#define DEVFN __device__ __forceinline__

typedef short bf16x8 __attribute__((ext_vector_type(8)));
typedef float f32x4  __attribute__((ext_vector_type(4)));
typedef int   i32x4  __attribute__((ext_vector_type(4)));

// problem constants
static constexpr int NTOK  = 64 * 196;   // 12544  (= 98 * 128)
static constexpr int DMODEL= 768;
static constexpr int NHEAD = 12;
static constexpr int NQKV  = 2304;       // 3*768 (= 18 * 128)
static constexpr int MMLP  = 3072;       // 4*768 (= 24 * 128)
static constexpr int SEQ   = 196;
static constexpr int NBATCH= 64;

// scale slots (absmax bits, atomicMax on uint reinterpretation of fp32)
enum { SL_LN1=0, SL_WQKV=1, SL_CTX=2, SL_WO=3, SL_LN2=4, SL_W1=5, SL_GELU=6, SL_W2=7 };

// ---- scattered absmax slots: 64 shadow copies per logical slot, 256B apart ----
static constexpr int NSH       = 64;     // shadow buckets per slot
static constexpr int SH_STRIDE = 64;     // uints between buckets (256 B lines)
static constexpr int SLOTS_U32 = NSH * SH_STRIDE;   // 4096 uints = 16 KB

DEVFN float bf2f(unsigned short u){ return __uint_as_float(((unsigned)u) << 16); }
// hardware packed f32->bf16 RNE: dst[15:0]=bf16(a), dst[31:16]=bf16(b)
DEVFN unsigned cvt_pk_bf16(float a, float b){
  unsigned r;
  asm("v_cvt_pk_bf16_f32 %0, %1, %2" : "=v"(r) : "v"(a), "v"(b));
  return r;
}
// split a pair into (packed hi, packed lo) with exact fp32 residuals
DEVFN void split_pk(float a, float b, unsigned& hp, unsigned& lp){
  hp = cvt_pk_bf16(a, b);
  float ra = a - __uint_as_float(hp << 16);
  float rb = b - __uint_as_float(hp & 0xffff0000u);
  lp = cvt_pk_bf16(ra, rb);
}
DEVFN float slot_absmax(const unsigned* __restrict__ slots, int slot){
  unsigned m = 0u;
#pragma unroll
  for (int j = 0; j < NSH; j++){
    unsigned u = slots[j * SH_STRIDE + slot];  // uniform scalar loads, L2-hot
    m = (u > m) ? u : m;                       // bits >=0: uint order == float order
  }
  return __uint_as_float(m);
}
DEVFN float slot_scale(const unsigned* __restrict__ slots, int slot){
  return fmaxf(slot_absmax(slots, slot) / 127.0f, 1e-8f);   // exact match to ref: max/127.0
}
DEVFN void scatter_amax(unsigned* slots, int slot, unsigned bucket, float v){
  atomicMax(slots + (bucket & (NSH - 1)) * SH_STRIDE + slot, __float_as_uint(v));
}
DEVFN float quantval(float x, float s){        // integer-valued quantized result
  float q = rintf(x / s);                      // RNE, matches jnp.round
  return fminf(fmaxf(q, -128.0f), 127.0f);
}
DEVFN unsigned pack4(float a, float b, float c, float d){
  return  ((unsigned)(unsigned char)(char)(int)a)
        | ((unsigned)(unsigned char)(char)(int)b << 8)
        | ((unsigned)(unsigned char)(char)(int)c << 16)
        | ((unsigned)(unsigned char)(char)(int)d << 24);
}
// exact-GELU with branch-free A&S 7.1.26 erf (max abs err 1.5e-7, invisible
// under the immediate bf16 rounding of the result).
DEVFN float gelu_fast(float v){
  float s  = v * 0.70710678118654752f;
  float ax = fabsf(s);
  float t  = __builtin_amdgcn_rcpf(fmaf(0.3275911f, ax, 1.0f));
  float p  = t * fmaf(t, fmaf(t, fmaf(t, fmaf(t, 1.061405429f, -1.453152027f),
                                      1.421413741f), -0.284496736f), 0.254829592f);
  float er = fmaf(-p, __expf(-ax * ax), 1.0f);           // erf(|s|) in [0,1)
  unsigned sgn = __float_as_uint(s) & 0x80000000u;
  er = __uint_as_float(__float_as_uint(er) | sgn);
  return 0.5f * v * (1.0f + er);
}
DEVFN f32x4 mfma16(bf16x8 a, bf16x8 b, f32x4 c){
  return __builtin_amdgcn_mfma_f32_16x16x32_bf16(a, b, c, 0, 0, 0);
}
DEVFN i32x4 mfma16i8(i32x4 a, i32x4 b, i32x4 c){
  return __builtin_amdgcn_mfma_i32_16x16x64_i8(a, b, c, 0, 0, 0);
}
DEVFN void async_ld16(const void* g, void* lds){
  __builtin_amdgcn_global_load_lds((const __attribute__((address_space(1))) void*)g,
                                   (__attribute__((address_space(3))) void*)lds, 16, 0, 0);
}
// V^T LDS layout: stride 256 ushorts + XOR swizzle on s-bits 3..5.
DEVFN int vidx(int d, int s){
  return d * 256 + (s ^ (((d ^ (d >> 2)) & 7) << 3));
}
// bijective XCD-chunked block swizzle (m204): consecutive tiles land on the same XCD's L2
DEVFN void xcd_swizzle(int gx, int gy, int& bx, int& by){
  int nwg = gx * gy;
  int bid = blockIdx.y * gx + blockIdx.x;
  int q = nwg >> 3, r = nwg & 7;
  int xcd = bid & 7, loc = bid >> 3;
  int sw = (xcd < r) ? (xcd * (q + 1) + loc) : (r * (q + 1) + (xcd - r) * q + loc);
  bx = sw % gx; by = sw / gx;
}

// ---------------- init scale slots ----------------
__global__ void k_init(unsigned* slots){
  int i = blockIdx.x * blockDim.x + threadIdx.x;
  if (i < SLOTS_U32) slots[i] = 0u;
}

// ---------------- fused absmax of the 4 weight tensors (1 launch) ----------------
__global__ void k_absmax4(const float* __restrict__ x0, const float* __restrict__ x1,
                          const float* __restrict__ x2, const float* __restrict__ x3,
                          unsigned* slots){
  int bid = blockIdx.x;
  const float* x; int n4, slot, b0, nb;
  if (bid < 256)      { x = x0; n4 = DMODEL * NQKV  / 4; slot = SL_WQKV; b0 = 0;   nb = 256; }
  else if (bid < 384) { x = x1; n4 = DMODEL * DMODEL/ 4; slot = SL_WO;   b0 = 256; nb = 128; }
  else if (bid < 640) { x = x2; n4 = DMODEL * MMLP  / 4; slot = SL_W1;   b0 = 384; nb = 256; }
  else                { x = x3; n4 = MMLP   * DMODEL/ 4; slot = SL_W2;   b0 = 640; nb = 256; }
  int lb = bid - b0;
  float m = 0.f;
  const float4* x4 = (const float4*)x;
  int stride = nb * blockDim.x;
  for (int j = lb * blockDim.x + threadIdx.x; j < n4; j += stride){
    float4 v = x4[j];
    m = fmaxf(m, fmaxf(fmaxf(fabsf(v.x), fabsf(v.y)), fmaxf(fabsf(v.z), fabsf(v.w))));
  }
  for (int off = 32; off; off >>= 1) m = fmaxf(m, __shfl_xor(m, off));
  __shared__ float wm[4];
  int lane = threadIdx.x & 63, w = threadIdx.x >> 6;
  if (lane == 0) wm[w] = m;
  __syncthreads();
  if (threadIdx.x == 0){
    float bm = fmaxf(fmaxf(wm[0], wm[1]), fmaxf(wm[2], wm[3]));
    scatter_amax(slots, slot, bid, bm);
  }
}

// ---------------- quantize 4 weights (K x N fp32) -> transposed int8 (N x K), 1 launch --------
__global__ void k_quant_transpose4(const float* __restrict__ w0, const float* __restrict__ w1,
                                   const float* __restrict__ w2, const float* __restrict__ w3,
                                   char* __restrict__ t0, char* __restrict__ t1,
                                   char* __restrict__ t2, char* __restrict__ t3,
                                   const unsigned* __restrict__ slots){
  // seg tile counts: qkv 72x24=1728 | wo 24x24=576 | w1 96x24=2304 | w2 24x96=2304
  int bid = blockIdx.x;
  const float* w; char* wt; int K, N, slot, lb;
  if (bid < 1728)      { w = w0; wt = t0; K = DMODEL; N = NQKV;   slot = SL_WQKV; lb = bid; }
  else if (bid < 2304) { w = w1; wt = t1; K = DMODEL; N = DMODEL; slot = SL_WO;   lb = bid - 1728; }
  else if (bid < 4608) { w = w2; wt = t2; K = DMODEL; N = MMLP;   slot = SL_W1;   lb = bid - 2304; }
  else                 { w = w3; wt = t3; K = MMLP;   N = DMODEL; slot = SL_W2;   lb = bid - 4608; }
  int nx = N / 32;
  int bx = lb % nx, by = lb / nx;

  __shared__ float tile[32][33];
  float s = slot_scale(slots, slot);
  int n0 = bx * 32, k0 = by * 32;
  int tx = threadIdx.x & 31, ty = threadIdx.x >> 5;   // 256 threads: ty 0..7
#pragma unroll
  for (int i = 0; i < 4; i++){
    int k = k0 + ty + i * 8;
    float v = w[(size_t)k * N + n0 + tx];
    tile[ty + i * 8][tx] = quantval(v, s);
  }
  __syncthreads();
  int n = threadIdx.x >> 3, kg = threadIdx.x & 7;
  unsigned o = pack4(tile[kg * 4 + 0][n], tile[kg * 4 + 1][n],
                     tile[kg * 4 + 2][n], tile[kg * 4 + 3][n]);
  *(unsigned*)(wt + (size_t)(n0 + n) * K + k0 + kg * 4) = o;
}

// ---------------- layernorm (rows of 768) + absmax ----------------
__global__ void k_layernorm(const float* __restrict__ x, const float* __restrict__ g,
                            const float* __restrict__ b, float* __restrict__ out,
                            unsigned* slots, int slot){
  int w = threadIdx.x >> 6, lane = threadIdx.x & 63;
  int row = blockIdx.x * 4 + w;
  const float4* xr = (const float4*)(x + (size_t)row * DMODEL);
  float4 v[3];
  float sum = 0.f;
#pragma unroll
  for (int i = 0; i < 3; i++){ v[i] = xr[i * 64 + lane]; sum += v[i].x + v[i].y + v[i].z + v[i].w; }
  for (int off = 32; off; off >>= 1) sum += __shfl_xor(sum, off);
  float mu = sum * (1.0f / 768.0f);
  float vs = 0.f;
#pragma unroll
  for (int i = 0; i < 3; i++){
    float dx = v[i].x - mu, dy = v[i].y - mu, dz = v[i].z - mu, dw = v[i].w - mu;
    vs += dx * dx + dy * dy + dz * dz + dw * dw;
  }
  for (int off = 32; off; off >>= 1) vs += __shfl_xor(vs, off);
  float inv = 1.0f / sqrtf(vs * (1.0f / 768.0f) + 1e-5f);
  const float4* g4 = (const float4*)g; const float4* b4 = (const float4*)b;
  float4* o4 = (float4*)(out + (size_t)row * DMODEL);
  float am = 0.f;
#pragma unroll
  for (int i = 0; i < 3; i++){
    float4 gg = g4[i * 64 + lane], bb = b4[i * 64 + lane], o;
    o.x = (v[i].x - mu) * inv * gg.x + bb.x;
    o.y = (v[i].y - mu) * inv * gg.y + bb.y;
    o.z = (v[i].z - mu) * inv * gg.z + bb.z;
    o.w = (v[i].w - mu) * inv * gg.w + bb.w;
    am = fmaxf(am, fmaxf(fmaxf(fabsf(o.x), fabsf(o.y)), fmaxf(fabsf(o.z), fabsf(o.w))));
    o4[i * 64 + lane] = o;
  }
  for (int off = 32; off; off >>= 1) am = fmaxf(am, __shfl_xor(am, off));
  __shared__ float am4[4];
  if (lane == 0) am4[w] = am;
  __syncthreads();
  if (threadIdx.x == 0){
    float bm = fmaxf(fmaxf(am4[0], am4[1]), fmaxf(am4[2], am4[3]));
    scatter_amax(slots, slot, blockIdx.x, bm);
  }
}

// ---------------- quantize fp32 activations -> packed int8 ----------------
__global__ void k_quant_act(const float* __restrict__ x, unsigned* __restrict__ out,
                            int n4, const unsigned* __restrict__ slots, int slot){
  float s = slot_scale(slots, slot);
  const float4* x4 = (const float4*)x;
  int stride = gridDim.x * blockDim.x;
  for (int j = blockIdx.x * blockDim.x + threadIdx.x; j < n4; j += stride){
    float4 v = x4[j];
    out[j] = pack4(quantval(v.x, s), quantval(v.y, s), quantval(v.z, s), quantval(v.w, s));
  }
}

// ---------------- quantize bf16 activations -> packed int8 ----------------
__global__ void k_quant_bf16_i8(const unsigned short* __restrict__ x, unsigned* __restrict__ out,
                                int n4, const unsigned* __restrict__ slots, int slot){
  float s = slot_scale(slots, slot);
  const ushort4* x4 = (const ushort4*)x;
  int stride = gridDim.x * blockDim.x;
  for (int j = blockIdx.x * blockDim.x + threadIdx.x; j < n4; j += stride){
    ushort4 v = x4[j];
    out[j] = pack4(quantval(bf2f(v.x), s), quantval(bf2f(v.y), s),
                   quantval(bf2f(v.z), s), quantval(bf2f(v.w), s));
  }
}

// ---------------- int8 GEMM: C[M,N] = sa*sb * (A[M,K] @ Bt[N,K]^T) + bias (+res / gelu) ---------
template<int EPI>
__launch_bounds__(256, 4)
__global__ void k_gemm(const char* __restrict__ A,    // M x K int8
                       const char* __restrict__ Bt,   // N x K int8
                       const float* __restrict__ bias,
                       const float* __restrict__ res,
                       float* __restrict__ Cf,
                       unsigned short* __restrict__ Cb,
                       const unsigned* __restrict__ slots, int sa_slot, int sb_slot,
                       unsigned* gmax_slots, int gmax_slot,
                       int M, int N, int K)
{
  __shared__ __align__(16) char smem[32768];
  __shared__ float gm4[4];
  const int tid  = threadIdx.x;
  const int lane = tid & 63;
  const int wv   = tid >> 6;        // 0..3
  const int wx   = wv & 1, wy = wv >> 1;
  const int quad = lane >> 4;
  const int l16  = lane & 15;
  int bx, by;
  xcd_swizzle(gridDim.x, gridDim.y, bx, by);   // XCD-local tile chunks (A-panel L2 reuse)
  const int m0 = by * 128, n0 = bx * 128;

  auto issue = [&](int k0, int buf){
#pragma unroll
    for (int i = 0; i < 2; i++){     // A tile: 512 chunks of 16B (row = c>>2, q = c&3)
      int c = tid + i * 256;
      int row = c >> 2, q = c & 3;
      int qs = (q - ((row + (row >> 2)) & 3)) & 3;   // inverse chunk rotation
      async_ld16(A + (size_t)(m0 + row) * K + k0 + qs * 16,
                 smem + buf * 8192 + (i * 256 + wv * 64) * 16);
    }
#pragma unroll
    for (int i = 0; i < 2; i++){     // B tile
      int c = tid + i * 256;
      int row = c >> 2, q = c & 3;
      int qs = (q - ((row + (row >> 2)) & 3)) & 3;
      async_ld16(Bt + (size_t)(n0 + row) * K + k0 + qs * 16,
                 smem + 16384 + buf * 8192 + (i * 256 + wv * 64) * 16);
    }
  };

  i32x4 acc[4][4] = {};
  const int nk = K >> 6;
  issue(0, 0);

  const int ch = (((quad + (l16 & 3) + (l16 >> 2)) & 3)) * 16;

  for (int k = 0; k < nk; k++){
    const int cur = k & 1;
    if (k + 1 < nk){
      issue((k + 1) << 6, cur ^ 1);                       // prefetch next tile
      asm volatile("s_waitcnt vmcnt(4)" ::: "memory");    // tile-k loads landed; k+1 in flight
    } else {
      asm volatile("s_waitcnt vmcnt(0)" ::: "memory");
    }
    asm volatile("s_barrier" ::: "memory");               // tile-k visible to all waves

    const char* Ab = smem + cur * 8192;
    const char* Bb = smem + 16384 + cur * 8192;
    i32x4 af[4], bfr[4];
#pragma unroll
    for (int i = 0; i < 4; i++)
      af[i] = *(const i32x4*)(Ab + (wy * 64 + i * 16 + l16) * 64 + ch);
#pragma unroll
    for (int j = 0; j < 4; j++)
      bfr[j] = *(const i32x4*)(Bb + (wx * 64 + j * 16 + l16) * 64 + ch);
    asm volatile("s_waitcnt lgkmcnt(0)" ::: "memory");    // frags in regs
    asm volatile("s_barrier" ::: "memory");               // all reads of cur done

#pragma unroll
    for (int i = 0; i < 4; i++)
#pragma unroll
      for (int j = 0; j < 4; j++)
        acc[i][j] = mfma16i8(af[i], bfr[j], acc[i][j]);
  }
  __syncthreads();   // all waves out of the K-loop before stage overlay is used

  // ---- epilogue: 4 slices of 32 rows; LDS transpose -> coalesced wide loads/stores ----
  float (*stage)[132] = (float (*)[132])smem;   // 16896 B, overlays dead tile buffers
  const float sc = slot_scale(slots, sa_slot) * slot_scale(slots, sb_slot);
  const int col4 = (tid & 31) * 4;           // 0..124
  const int gc   = n0 + col4;
  const float4 bb = *(const float4*)&bias[gc];
  float gmax = 0.f;
#pragma unroll
  for (int i = 0; i < 4; i++){
#pragma unroll
    for (int j = 0; j < 4; j++)
#pragma unroll
      for (int r = 0; r < 4; r++)
        stage[wy * 16 + quad * 4 + r][wx * 64 + j * 16 + l16] = (float)acc[i][j][r];
    __syncthreads();
#pragma unroll
    for (int rr = 0; rr < 4; rr++){
      const int rl = rr * 8 + (tid >> 5);                       // 0..31
      const int gm = m0 + ((rl >> 4) * 64) + i * 16 + (rl & 15);
      float4 v = *(const float4*)&stage[rl][col4];
      v.x = v.x * sc + bb.x; v.y = v.y * sc + bb.y;
      v.z = v.z * sc + bb.z; v.w = v.w * sc + bb.w;
      if constexpr (EPI == 1){
        float4 rv = *(const float4*)&res[(size_t)gm * N + gc];
        v.x += rv.x; v.y += rv.y; v.z += rv.z; v.w += rv.w;
        *(float4*)&Cf[(size_t)gm * N + gc] = v;
      } else if constexpr (EPI == 2){
        float g0 = gelu_fast(v.x);
        float g1 = gelu_fast(v.y);
        float g2 = gelu_fast(v.z);
        float g3 = gelu_fast(v.w);
        gmax = fmaxf(gmax, fmaxf(fmaxf(fabsf(g0), fabsf(g1)), fmaxf(fabsf(g2), fabsf(g3))));
        uint2 o = {cvt_pk_bf16(g0, g1), cvt_pk_bf16(g2, g3)};   // HW RNE, 2 insts for 4 elems
        *(uint2*)&Cb[(size_t)gm * N + gc] = o;
      } else {
        *(float4*)&Cf[(size_t)gm * N + gc] = v;
      }
    }
    __syncthreads();
  }
  if constexpr (EPI == 2){
    for (int off = 32; off; off >>= 1) gmax = fmaxf(gmax, __shfl_xor(gmax, off));
    if (lane == 0) gm4[wv] = gmax;
    __syncthreads();
    if (tid == 0){
      float bm = fmaxf(fmaxf(gm4[0], gm4[1]), fmaxf(gm4[2], gm4[3]));
      scatter_amax(gmax_slots, gmax_slot, blockIdx.x + blockIdx.y * gridDim.x, bm);
    }
  }
}

// ---------------- attention: one block per (b,h), 13 waves, ONE q-tile per wave ----------------
__launch_bounds__(832, 4)
__global__ void k_attention(const float* __restrict__ qkv, float* __restrict__ ctx,
                            unsigned* slots){
  __shared__ __align__(16) unsigned short Khi[208 * 72], Klo[208 * 72];   // 59,904 B
  __shared__ __align__(16) unsigned short Vhi[64 * 256], Vlo[64 * 256];   // 65,536 B (swizzled)
  __shared__ __align__(16) unsigned short Ps[13][2][16 * 40];             // 33,280 B (per-wave hi/lo)
  __shared__ float gm[13];

  const int bh = blockIdx.x;
  const int b = bh / NHEAD, h = bh % NHEAD;
  const float* base = qkv + (size_t)b * SEQ * NQKV;
  const int tid = threadIdx.x, lane = tid & 63, wv = tid >> 6;   // wv 0..12
  const int quad = lane >> 4, l16 = lane & 15;

  // ---- prefetch ALL K/V global data into registers, then convert+write LDS ----
  float4 kreg[4], vreg[5];
#pragma unroll
  for (int i = 0; i < 4; i++){
    int idx = tid + i * 832;                  // K: 208*16 = 3328 chunks (4*832 exact)
    int r = idx >> 4, c4 = (idx & 15) * 4;
    float4 v = {0.f, 0.f, 0.f, 0.f};
    if (r < SEQ) v = *(const float4*)(base + (size_t)r * NQKV + DMODEL + h * 64 + c4);
    kreg[i] = v;
  }
#pragma unroll
  for (int i = 0; i < 5; i++){
    int idx = tid + i * 832;                  // V: 232*16 = 3712 chunks (incl. zero pad)
    int s = idx >> 4, dg = (idx & 15) * 4;
    float4 v = {0.f, 0.f, 0.f, 0.f};
    if (idx < 232 * 16 && s < SEQ)
      v = *(const float4*)(base + (size_t)s * NQKV + 2 * DMODEL + h * 64 + dg);
    vreg[i] = v;
  }
#pragma unroll
  for (int i = 0; i < 4; i++){
    int idx = tid + i * 832;
    int r = idx >> 4, c4 = (idx & 15) * 4;
    float4 v = kreg[i];
    unsigned h01, l01, h23, l23;
    split_pk(v.x, v.y, h01, l01);
    split_pk(v.z, v.w, h23, l23);
    *(uint2*)(Khi + r * 72 + c4) = uint2{h01, h23};
    *(uint2*)(Klo + r * 72 + c4) = uint2{l01, l23};
  }
#pragma unroll
  for (int i = 0; i < 5; i++){
    int idx = tid + i * 832;
    if (idx < 232 * 16){
      int s = idx >> 4, dg = (idx & 15) * 4;
      float4 v = vreg[i];
      unsigned h01, l01, h23, l23;
      split_pk(v.x, v.y, h01, l01);
      split_pk(v.z, v.w, h23, l23);
      Vhi[vidx(dg + 0, s)] = (unsigned short)h01; Vhi[vidx(dg + 1, s)] = (unsigned short)(h01 >> 16);
      Vhi[vidx(dg + 2, s)] = (unsigned short)h23; Vhi[vidx(dg + 3, s)] = (unsigned short)(h23 >> 16);
      Vlo[vidx(dg + 0, s)] = (unsigned short)l01; Vlo[vidx(dg + 1, s)] = (unsigned short)(l01 >> 16);
      Vlo[vidx(dg + 2, s)] = (unsigned short)l23; Vlo[vidx(dg + 3, s)] = (unsigned short)(l23 >> 16);
    }
  }
  __syncthreads();    // the ONLY full-block barrier in the main body

  unsigned short* PsH = &Ps[wv][0][0];
  unsigned short* PsL = &Ps[wv][1][0];

  float gmax = 0.f;
  const int qt = wv;                 // one q-tile per wave
  {
    const int q0 = qt * 16;
    const int sq = q0 + l16;
    const bool valid = sq < SEQ;

    // Q fragments straight from global (A-layout: m=l16, k=quad*8+j), split hi/lo packed
    bf16x8 aqh[2], aql[2];
    const float* qrow = base + (size_t)(valid ? sq : 0) * NQKV + h * 64;
#pragma unroll
    for (int ks = 0; ks < 2; ks++){
      float4 v0 = {0,0,0,0}, v1 = {0,0,0,0};
      if (valid){
        v0 = *(const float4*)(qrow + ks * 32 + quad * 8);
        v1 = *(const float4*)(qrow + ks * 32 + quad * 8 + 4);
      }
      unsigned* ah = (unsigned*)&aqh[ks];
      unsigned* al = (unsigned*)&aql[ks];
      split_pk(v0.x, v0.y, ah[0], al[0]);
      split_pk(v0.z, v0.w, ah[1], al[1]);
      split_pk(v1.x, v1.y, ah[2], al[2]);
      split_pk(v1.z, v1.w, ah[3], al[3]);
    }

    // ---- S = Q K^T / 8 : 13 independent MFMA chains ----
    f32x4 sacc[13];
    __builtin_amdgcn_s_setprio(1);
#pragma unroll
    for (int t = 0; t < 13; t++){
      f32x4 a = {0.f, 0.f, 0.f, 0.f};
#pragma unroll
      for (int ks = 0; ks < 2; ks++){
        bf16x8 bkh = *(const bf16x8*)(Khi + (t * 16 + l16) * 72 + ks * 32 + quad * 8);
        bf16x8 bkl = *(const bf16x8*)(Klo + (t * 16 + l16) * 72 + ks * 32 + quad * 8);
        a = mfma16(aqh[ks], bkh, a);
        a = mfma16(aqh[ks], bkl, a);
        a = mfma16(aql[ks], bkh, a);
      }
      sacc[t] = a;
    }
    __builtin_amdgcn_s_setprio(0);

    // ---- softmax in registers: lane holds rows q=quad*4+r, cols s=t*16+l16 ----
    float mx[4] = {-1e30f, -1e30f, -1e30f, -1e30f};
#pragma unroll
    for (int t = 0; t < 13; t++){
      bool dead = (t == 12) && (l16 >= 4);   // key col >= 196
#pragma unroll
      for (int r = 0; r < 4; r++){
        float v = dead ? -1e30f : sacc[t][r] * 0.125f;
        sacc[t][r] = v;
        mx[r] = fmaxf(mx[r], v);
      }
    }
#pragma unroll
    for (int off = 1; off < 16; off <<= 1)
#pragma unroll
      for (int r = 0; r < 4; r++) mx[r] = fmaxf(mx[r], __shfl_xor(mx[r], off));
    float sum[4] = {0.f, 0.f, 0.f, 0.f};
#pragma unroll
    for (int t = 0; t < 13; t++)
#pragma unroll
      for (int r = 0; r < 4; r++){
        float e = __expf(sacc[t][r] - mx[r]);
        sacc[t][r] = e; sum[r] += e;
      }
#pragma unroll
    for (int off = 1; off < 16; off <<= 1)
#pragma unroll
      for (int r = 0; r < 4; r++) sum[r] += __shfl_xor(sum[r], off);
    float inv[4];
#pragma unroll
    for (int r = 0; r < 4; r++) inv[r] = 1.0f / sum[r];

    // ---- O = P V : per-ks transpose C->A layout through per-wave scratch, no barrier ----
    f32x4 oacc[4] = {};
#pragma unroll
    for (int ks = 0; ks < 7; ks++){
      const int t0 = 2 * ks, t1 = 2 * ks + 1;
#pragma unroll
      for (int r = 0; r < 4; r++){
        int row = quad * 4 + r;
        float a = sacc[t0][r] * inv[r];
        float c = (t1 < 13) ? sacc[t1][r] * inv[r] : 0.f;   // bf16(0)=0 handles the pad
        unsigned hp, lp;
        split_pk(a, c, hp, lp);
        PsH[row * 40 + l16]      = (unsigned short)hp;
        PsH[row * 40 + 16 + l16] = (unsigned short)(hp >> 16);
        PsL[row * 40 + l16]      = (unsigned short)lp;
        PsL[row * 40 + 16 + l16] = (unsigned short)(lp >> 16);
      }
      __builtin_amdgcn_wave_barrier();   // keep compiler from reordering the RAW through LDS
      bf16x8 aph = *(const bf16x8*)(PsH + l16 * 40 + quad * 8);
      bf16x8 apl = *(const bf16x8*)(PsL + l16 * 40 + quad * 8);
      __builtin_amdgcn_s_setprio(1);
#pragma unroll
      for (int n = 0; n < 4; n++){
        bf16x8 bvh = *(const bf16x8*)(Vhi + vidx(n * 16 + l16, ks * 32 + quad * 8));
        bf16x8 bvl = *(const bf16x8*)(Vlo + vidx(n * 16 + l16, ks * 32 + quad * 8));
        oacc[n] = mfma16(aph, bvh, oacc[n]);
        oacc[n] = mfma16(aph, bvl, oacc[n]);
        oacc[n] = mfma16(apl, bvh, oacc[n]);
      }
      __builtin_amdgcn_s_setprio(0);
      __builtin_amdgcn_wave_barrier();   // reads of this slice complete before next-iter writes
    }

    // ---- store ctx (C-layout: row=quad*4+r, col=n*16+l16) + absmax ----
#pragma unroll
    for (int r = 0; r < 4; r++){
      int srow = q0 + quad * 4 + r;
      if (srow < SEQ){
#pragma unroll
        for (int n = 0; n < 4; n++){
          float v = oacc[n][r];
          ctx[((size_t)(b * SEQ + srow)) * DMODEL + h * 64 + n * 16 + l16] = v;
          gmax = fmaxf(gmax, fabsf(v));
        }
      }
    }
  }
  for (int off = 32; off; off >>= 1) gmax = fmaxf(gmax, __shfl_xor(gmax, off));
  if (lane == 0) gm[wv] = gmax;
  __syncthreads();
  if (tid == 0){
    float bm = 0.f;
#pragma unroll
    for (int i = 0; i < 13; i++) bm = fmaxf(bm, gm[i]);
    scatter_amax(slots, SL_CTX, blockIdx.x, bm);
  }
}

// ---------------- launch ----------------
extern "C" void kernel_launch(void* const* d_in, const int* in_sizes, int n_in,
                              void* d_out, int out_size, void* d_ws, size_t ws_size,
                              hipStream_t stream)
{
  const float* x     = (const float*)d_in[0];
  const float* ln1_g = (const float*)d_in[1];
  const float* ln1_b = (const float*)d_in[2];
  const float* ln2_g = (const float*)d_in[3];
  const float* ln2_b = (const float*)d_in[4];
  const float* w_qkv = (const float*)d_in[5];
  const float* b_qkv = (const float*)d_in[6];
  const float* w_o   = (const float*)d_in[7];
  const float* b_o   = (const float*)d_in[8];
  const float* w1    = (const float*)d_in[9];
  const float* b1    = (const float*)d_in[10];
  const float* w2    = (const float*)d_in[11];
  const float* b2    = (const float*)d_in[12];

  char* ws = (char*)d_ws;
  size_t off = 0;
  unsigned* slots = (unsigned*)ws;                 off += SLOTS_U32 * 4;   // 16 KB scattered slots
  char* wqkvT = (char*)(ws + off); off += (size_t)NQKV  * DMODEL;
  char* woT   = (char*)(ws + off); off += (size_t)DMODEL* DMODEL;
  char* w1T   = (char*)(ws + off); off += (size_t)MMLP  * DMODEL;
  char* w2T   = (char*)(ws + off); off += (size_t)DMODEL* MMLP;
  off = (off + 255) & ~(size_t)255;
  float* t1    = (float*)(ws + off);               off += (size_t)NTOK * DMODEL * 4;
  char*  t1q   = (char*)(ws + off);                off += (size_t)NTOK * DMODEL;
  off = (off + 255) & ~(size_t)255;
  float* qkv   = (float*)(ws + off);               off += (size_t)NTOK * NQKV * 4;
  float* xmid  = (float*)(ws + off);               off += (size_t)NTOK * DMODEL * 4;
  // FC1 bf16 output (77.07 MB) + its int8 quant (38.54 MB) exactly fill the qkv region (115.6 MB)
  unsigned short* h1 = (unsigned short*)qkv;
  char* h1q = (char*)qkv + (size_t)NTOK * MMLP * 2;
  float* outp = (float*)d_out;

  k_init<<<(SLOTS_U32 + 255) / 256, 256, 0, stream>>>(slots);

  k_absmax4<<<896, 256, 0, stream>>>(w_qkv, w_o, w1, w2, slots);

  k_quant_transpose4<<<6912, 256, 0, stream>>>(w_qkv, w_o, w1, w2,
                                               wqkvT, woT, w1T, w2T, slots);

  // LN1 -> quant -> QKV
  k_layernorm<<<NTOK / 4, 256, 0, stream>>>(x, ln1_g, ln1_b, t1, slots, SL_LN1);
  {
    int n4 = NTOK * DMODEL / 4;
    k_quant_act<<<2048, 256, 0, stream>>>(t1, (unsigned*)t1q, n4, slots, SL_LN1);
  }
  k_gemm<0><<<dim3(NQKV / 128, NTOK / 128), 256, 0, stream>>>(
      t1q, wqkvT, b_qkv, nullptr, qkv, nullptr, slots, SL_LN1, SL_WQKV, nullptr, 0,
      NTOK, NQKV, DMODEL);

  // attention -> ctx (t1) + absmax
  k_attention<<<NBATCH * NHEAD, 832, 0, stream>>>(qkv, t1, slots);
  {
    int n4 = NTOK * DMODEL / 4;
    k_quant_act<<<2048, 256, 0, stream>>>(t1, (unsigned*)t1q, n4, slots, SL_CTX);
  }
  // O-proj + residual -> xmid
  k_gemm<1><<<dim3(DMODEL / 128, NTOK / 128), 256, 0, stream>>>(
      t1q, woT, b_o, x, xmid, nullptr, slots, SL_CTX, SL_WO, nullptr, 0,
      NTOK, DMODEL, DMODEL);

  // LN2 -> quant -> FC1(+gelu->bf16) -> quant -> FC2 + residual -> out
  k_layernorm<<<NTOK / 4, 256, 0, stream>>>(xmid, ln2_g, ln2_b, t1, slots, SL_LN2);
  {
    int n4 = NTOK * DMODEL / 4;
    k_quant_act<<<2048, 256, 0, stream>>>(t1, (unsigned*)t1q, n4, slots, SL_LN2);
  }
  k_gemm<2><<<dim3(MMLP / 128, NTOK / 128), 256, 0, stream>>>(
      t1q, w1T, b1, nullptr, nullptr, h1, slots, SL_LN2, SL_W1, slots, SL_GELU,
      NTOK, MMLP, DMODEL);
  {
    int n4 = NTOK * MMLP / 4;
    k_quant_bf16_i8<<<2048, 256, 0, stream>>>(h1, (unsigned*)h1q, n4, slots, SL_GELU);
  }
  k_gemm<1><<<dim3(DMODEL / 128, NTOK / 128), 256, 0, stream>>>(
      h1q, w2T, b2, xmid, outp, nullptr, slots, SL_GELU, SL_W2, nullptr, 0,
      NTOK, DMODEL, MMLP);
}

// Round 8
// 428.311 us; speedup vs baseline: 1.1861x; 1.0354x over previous
//
#include <hip/hip_runtime.h>
#include <cstdint>
#include <cstddef>

#define DEVFN __device__ __forceinline__

typedef short bf16x8 __attribute__((ext_vector_type(8)));
typedef float f32x4  __attribute__((ext_vector_type(4)));
typedef int   i32x4  __attribute__((ext_vector_type(4)));

// problem constants
static constexpr int NTOK  = 64 * 196;   // 12544  (= 98 * 128)
static constexpr int DMODEL= 768;
static constexpr int NHEAD = 12;
static constexpr int NQKV  = 2304;       // 3*768 (= 18 * 128)
static constexpr int MMLP  = 3072;       // 4*768 (= 24 * 128)
static constexpr int SEQ   = 196;
static constexpr int NBATCH= 64;

// scale slots (absmax bits, atomicMax on uint reinterpretation of fp32)
enum { SL_LN1=0, SL_WQKV=1, SL_CTX=2, SL_WO=3, SL_LN2=4, SL_W1=5, SL_GELU=6, SL_W2=7 };

// ---- scattered absmax slots: 64 shadow copies per logical slot, 256B apart ----
static constexpr int NSH       = 64;     // shadow buckets per slot
static constexpr int SH_STRIDE = 64;     // uints between buckets (256 B lines)
static constexpr int SLOTS_U32 = NSH * SH_STRIDE;   // 4096 uints = 16 KB

DEVFN float bf2f(unsigned short u){ return __uint_as_float(((unsigned)u) << 16); }
// hardware packed f32->bf16 RNE: dst[15:0]=bf16(a), dst[31:16]=bf16(b)
DEVFN unsigned cvt_pk_bf16(float a, float b){
  unsigned r;
  asm("v_cvt_pk_bf16_f32 %0, %1, %2" : "=v"(r) : "v"(a), "v"(b));
  return r;
}
// split a pair into (packed hi, packed lo) with exact fp32 residuals
DEVFN void split_pk(float a, float b, unsigned& hp, unsigned& lp){
  hp = cvt_pk_bf16(a, b);
  float ra = a - __uint_as_float(hp << 16);
  float rb = b - __uint_as_float(hp & 0xffff0000u);
  lp = cvt_pk_bf16(ra, rb);
}
DEVFN float slot_absmax(const unsigned* __restrict__ slots, int slot){
  unsigned m = 0u;
#pragma unroll
  for (int j = 0; j < NSH; j++){
    unsigned u = slots[j * SH_STRIDE + slot];  // uniform scalar loads, L2-hot
    m = (u > m) ? u : m;                       // bits >=0: uint order == float order
  }
  return __uint_as_float(m);
}
DEVFN float slot_scale(const unsigned* __restrict__ slots, int slot){
  return fmaxf(slot_absmax(slots, slot) / 127.0f, 1e-8f);   // exact match to ref: max/127.0
}
DEVFN void scatter_amax(unsigned* slots, int slot, unsigned bucket, float v){
  atomicMax(slots + (bucket & (NSH - 1)) * SH_STRIDE + slot, __float_as_uint(v));
}
DEVFN float quantval(float x, float s){        // integer-valued quantized result
  float q = rintf(x / s);                      // RNE, matches jnp.round
  return fminf(fmaxf(q, -128.0f), 127.0f);
}
DEVFN unsigned pack4(float a, float b, float c, float d){
  return  ((unsigned)(unsigned char)(char)(int)a)
        | ((unsigned)(unsigned char)(char)(int)b << 8)
        | ((unsigned)(unsigned char)(char)(int)c << 16)
        | ((unsigned)(unsigned char)(char)(int)d << 24);
}
// exact-GELU with branch-free A&S 7.1.26 erf (max abs err 1.5e-7, invisible
// under the immediate bf16 rounding of the result).
DEVFN float gelu_fast(float v){
  float s  = v * 0.70710678118654752f;
  float ax = fabsf(s);
  float t  = __builtin_amdgcn_rcpf(fmaf(0.3275911f, ax, 1.0f));
  float p  = t * fmaf(t, fmaf(t, fmaf(t, fmaf(t, 1.061405429f, -1.453152027f),
                                      1.421413741f), -0.284496736f), 0.254829592f);
  float er = fmaf(-p, __expf(-ax * ax), 1.0f);           // erf(|s|) in [0,1)
  unsigned sgn = __float_as_uint(s) & 0x80000000u;
  er = __uint_as_float(__float_as_uint(er) | sgn);
  return 0.5f * v * (1.0f + er);
}
DEVFN f32x4 mfma16(bf16x8 a, bf16x8 b, f32x4 c){
  return __builtin_amdgcn_mfma_f32_16x16x32_bf16(a, b, c, 0, 0, 0);
}
DEVFN i32x4 mfma16i8(i32x4 a, i32x4 b, i32x4 c){
  return __builtin_amdgcn_mfma_i32_16x16x64_i8(a, b, c, 0, 0, 0);
}
DEVFN void async_ld16(const void* g, void* lds){
  __builtin_amdgcn_global_load_lds((const __attribute__((address_space(1))) void*)g,
                                   (__attribute__((address_space(3))) void*)lds, 16, 0, 0);
}
// V^T LDS layout: stride 256 ushorts + XOR swizzle on s-bits 3..5.
DEVFN int vidx(int d, int s){
  return d * 256 + (s ^ (((d ^ (d >> 2)) & 7) << 3));
}
// bijective XCD-chunked block swizzle (m204): consecutive tiles land on the same XCD's L2
DEVFN void xcd_swizzle(int gx, int gy, int& bx, int& by){
  int nwg = gx * gy;
  int bid = blockIdx.y * gx + blockIdx.x;
  int q = nwg >> 3, r = nwg & 7;
  int xcd = bid & 7, loc = bid >> 3;
  int sw = (xcd < r) ? (xcd * (q + 1) + loc) : (r * (q + 1) + (xcd - r) * q + loc);
  bx = sw % gx; by = sw / gx;
}

// ======== LN stats/quant split: LN writes only {mu,inv} per row (100 KB) + absmax; =========
// ======== the quant pass re-reads x (L3-hot) and recomputes the IDENTICAL expression ======
DEVFN float ln_stats_wave(const float* __restrict__ x, const float* __restrict__ g,
                          const float* __restrict__ b, float2* __restrict__ stats,
                          int row, int lane){
  const float4* xr = (const float4*)(x + (size_t)row * DMODEL);
  float4 v[3];
  float sum = 0.f;
#pragma unroll
  for (int i = 0; i < 3; i++){ v[i] = xr[i * 64 + lane]; sum += v[i].x + v[i].y + v[i].z + v[i].w; }
  for (int off = 32; off; off >>= 1) sum += __shfl_xor(sum, off);
  float mu = sum * (1.0f / 768.0f);
  float vs = 0.f;
#pragma unroll
  for (int i = 0; i < 3; i++){
    float dx = v[i].x - mu, dy = v[i].y - mu, dz = v[i].z - mu, dw = v[i].w - mu;
    vs += dx * dx + dy * dy + dz * dz + dw * dw;
  }
  for (int off = 32; off; off >>= 1) vs += __shfl_xor(vs, off);
  float inv = 1.0f / sqrtf(vs * (1.0f / 768.0f) + 1e-5f);
  const float4* g4 = (const float4*)g; const float4* b4 = (const float4*)b;
  float am = 0.f;
#pragma unroll
  for (int i = 0; i < 3; i++){
    float4 gg = g4[i * 64 + lane], bb = b4[i * 64 + lane];
    float ox = (v[i].x - mu) * inv * gg.x + bb.x;
    float oy = (v[i].y - mu) * inv * gg.y + bb.y;
    float oz = (v[i].z - mu) * inv * gg.z + bb.z;
    float ow = (v[i].w - mu) * inv * gg.w + bb.w;
    am = fmaxf(am, fmaxf(fmaxf(fabsf(ox), fabsf(oy)), fmaxf(fabsf(oz), fabsf(ow))));
  }
  if (lane == 0) stats[row] = float2{mu, inv};
  return am;
}
DEVFN void ln_quant_wave(const float* __restrict__ x, const float* __restrict__ g,
                         const float* __restrict__ b, const float2* __restrict__ stats,
                         char* __restrict__ outq, float s, int row, int lane){
  float2 st = stats[row];
  float mu = st.x, inv = st.y;
  const float4* xr = (const float4*)(x + (size_t)row * DMODEL);
  const float4* g4 = (const float4*)g; const float4* b4 = (const float4*)b;
  unsigned* oq = (unsigned*)(outq + (size_t)row * DMODEL);
#pragma unroll
  for (int i = 0; i < 3; i++){
    float4 v = xr[i * 64 + lane];
    float4 gg = g4[i * 64 + lane], bb = b4[i * 64 + lane];
    float ox = (v.x - mu) * inv * gg.x + bb.x;
    float oy = (v.y - mu) * inv * gg.y + bb.y;
    float oz = (v.z - mu) * inv * gg.z + bb.z;
    float ow = (v.w - mu) * inv * gg.w + bb.w;
    oq[i * 64 + lane] = pack4(quantval(ox, s), quantval(oy, s),
                              quantval(oz, s), quantval(ow, s));
  }
}

// ---------------- standalone LN stats / quant (used for LN2) ----------------
__global__ void k_ln_stats(const float* __restrict__ x, const float* __restrict__ g,
                           const float* __restrict__ b, float2* __restrict__ stats,
                           unsigned* slots, int slot){
  int w = threadIdx.x >> 6, lane = threadIdx.x & 63;
  int row = blockIdx.x * 4 + w;
  float am = ln_stats_wave(x, g, b, stats, row, lane);
  for (int off = 32; off; off >>= 1) am = fmaxf(am, __shfl_xor(am, off));
  __shared__ float am4[4];
  if (lane == 0) am4[w] = am;
  __syncthreads();
  if (threadIdx.x == 0){
    float bm = fmaxf(fmaxf(am4[0], am4[1]), fmaxf(am4[2], am4[3]));
    scatter_amax(slots, slot, blockIdx.x, bm);
  }
}
__global__ void k_ln_quant(const float* __restrict__ x, const float* __restrict__ g,
                           const float* __restrict__ b, const float2* __restrict__ stats,
                           char* __restrict__ outq, const unsigned* __restrict__ slots, int slot){
  int w = threadIdx.x >> 6, lane = threadIdx.x & 63;
  int row = blockIdx.x * 4 + w;
  float s = slot_scale(slots, slot);
  ln_quant_wave(x, g, b, stats, outq, s, row, lane);
}

// ---------------- prep1: weight absmax (blocks 0..895) || LN1 stats (blocks 896..4031) -------
__global__ void k_prep1(const float* __restrict__ w_qkv, const float* __restrict__ w_o,
                        const float* __restrict__ w1, const float* __restrict__ w2,
                        const float* __restrict__ x, const float* __restrict__ g,
                        const float* __restrict__ b, float2* __restrict__ stats,
                        unsigned* slots){
  __shared__ float red[4];
  int bid = blockIdx.x;
  int lane = threadIdx.x & 63, w = threadIdx.x >> 6;
  if (bid < 896){
    const float* xx; int n4, slot, b0, nb;
    if (bid < 256)      { xx = w_qkv; n4 = DMODEL * NQKV  / 4; slot = SL_WQKV; b0 = 0;   nb = 256; }
    else if (bid < 384) { xx = w_o;   n4 = DMODEL * DMODEL/ 4; slot = SL_WO;   b0 = 256; nb = 128; }
    else if (bid < 640) { xx = w1;    n4 = DMODEL * MMLP  / 4; slot = SL_W1;   b0 = 384; nb = 256; }
    else                { xx = w2;    n4 = MMLP   * DMODEL/ 4; slot = SL_W2;   b0 = 640; nb = 256; }
    int lb = bid - b0;
    float m = 0.f;
    const float4* x4 = (const float4*)xx;
    int stride = nb * blockDim.x;
    for (int j = lb * blockDim.x + threadIdx.x; j < n4; j += stride){
      float4 v = x4[j];
      m = fmaxf(m, fmaxf(fmaxf(fabsf(v.x), fabsf(v.y)), fmaxf(fabsf(v.z), fabsf(v.w))));
    }
    for (int off = 32; off; off >>= 1) m = fmaxf(m, __shfl_xor(m, off));
    if (lane == 0) red[w] = m;
    __syncthreads();
    if (threadIdx.x == 0){
      float bm = fmaxf(fmaxf(red[0], red[1]), fmaxf(red[2], red[3]));
      scatter_amax(slots, slot, bid, bm);
    }
  } else {
    int row = (bid - 896) * 4 + w;
    float am = ln_stats_wave(x, g, b, stats, row, lane);
    for (int off = 32; off; off >>= 1) am = fmaxf(am, __shfl_xor(am, off));
    if (lane == 0) red[w] = am;
    __syncthreads();
    if (threadIdx.x == 0){
      float bm = fmaxf(fmaxf(red[0], red[1]), fmaxf(red[2], red[3]));
      scatter_amax(slots, SL_LN1, bid, bm);
    }
  }
}

// ---------------- prep2: weight quant-transpose (0..6911) || LN1 quant (6912..10047) ---------
__global__ void k_prep2(const float* __restrict__ w0, const float* __restrict__ w1,
                        const float* __restrict__ w2, const float* __restrict__ w3,
                        char* __restrict__ t0, char* __restrict__ t1,
                        char* __restrict__ t2, char* __restrict__ t3,
                        const float* __restrict__ x, const float* __restrict__ g,
                        const float* __restrict__ b, const float2* __restrict__ stats,
                        char* __restrict__ outq, const unsigned* __restrict__ slots){
  __shared__ float tile[32][33];
  int bid = blockIdx.x;
  if (bid < 6912){
    const float* w; char* wt; int K, N, slot, lb;
    if (bid < 1728)      { w = w0; wt = t0; K = DMODEL; N = NQKV;   slot = SL_WQKV; lb = bid; }
    else if (bid < 2304) { w = w1; wt = t1; K = DMODEL; N = DMODEL; slot = SL_WO;   lb = bid - 1728; }
    else if (bid < 4608) { w = w2; wt = t2; K = DMODEL; N = MMLP;   slot = SL_W1;   lb = bid - 2304; }
    else                 { w = w3; wt = t3; K = MMLP;   N = DMODEL; slot = SL_W2;   lb = bid - 4608; }
    int nx = N / 32;
    int bx = lb % nx, by = lb / nx;
    float s = slot_scale(slots, slot);
    int n0 = bx * 32, k0 = by * 32;
    int tx = threadIdx.x & 31, ty = threadIdx.x >> 5;   // 256 threads: ty 0..7
#pragma unroll
    for (int i = 0; i < 4; i++){
      int k = k0 + ty + i * 8;
      float v = w[(size_t)k * N + n0 + tx];
      tile[ty + i * 8][tx] = quantval(v, s);
    }
    __syncthreads();
    int n = threadIdx.x >> 3, kg = threadIdx.x & 7;
    unsigned o = pack4(tile[kg * 4 + 0][n], tile[kg * 4 + 1][n],
                       tile[kg * 4 + 2][n], tile[kg * 4 + 3][n]);
    *(unsigned*)(wt + (size_t)(n0 + n) * K + k0 + kg * 4) = o;
  } else {
    int w = threadIdx.x >> 6, lane = threadIdx.x & 63;
    int row = (bid - 6912) * 4 + w;
    float s = slot_scale(slots, SL_LN1);
    ln_quant_wave(x, g, b, stats, outq, s, row, lane);
  }
}

// ---------------- quantize fp32 activations -> packed int8 (ctx path) ----------------
__global__ void k_quant_act(const float* __restrict__ x, unsigned* __restrict__ out,
                            int n4, const unsigned* __restrict__ slots, int slot){
  float s = slot_scale(slots, slot);
  const float4* x4 = (const float4*)x;
  int stride = gridDim.x * blockDim.x;
  for (int j = blockIdx.x * blockDim.x + threadIdx.x; j < n4; j += stride){
    float4 v = x4[j];
    out[j] = pack4(quantval(v.x, s), quantval(v.y, s), quantval(v.z, s), quantval(v.w, s));
  }
}

// ---------------- quantize bf16 activations -> packed int8 (gelu path) ----------------
__global__ void k_quant_bf16_i8(const unsigned short* __restrict__ x, unsigned* __restrict__ out,
                                int n4, const unsigned* __restrict__ slots, int slot){
  float s = slot_scale(slots, slot);
  const ushort4* x4 = (const ushort4*)x;
  int stride = gridDim.x * blockDim.x;
  for (int j = blockIdx.x * blockDim.x + threadIdx.x; j < n4; j += stride){
    ushort4 v = x4[j];
    out[j] = pack4(quantval(bf2f(v.x), s), quantval(bf2f(v.y), s),
                   quantval(bf2f(v.z), s), quantval(bf2f(v.w), s));
  }
}

// ---------------- int8 GEMM: C[M,N] = sa*sb * (A[M,K] @ Bt[N,K]^T) + bias (+res / gelu) ---------
template<int EPI>
__launch_bounds__(256, 4)
__global__ void k_gemm(const char* __restrict__ A,    // M x K int8
                       const char* __restrict__ Bt,   // N x K int8
                       const float* __restrict__ bias,
                       const float* __restrict__ res,
                       float* __restrict__ Cf,
                       unsigned short* __restrict__ Cb,
                       const unsigned* __restrict__ slots, int sa_slot, int sb_slot,
                       unsigned* gmax_slots, int gmax_slot,
                       int M, int N, int K)
{
  __shared__ __align__(16) char smem[32768];
  __shared__ float gm4[4];
  const int tid  = threadIdx.x;
  const int lane = tid & 63;
  const int wv   = tid >> 6;        // 0..3
  const int wx   = wv & 1, wy = wv >> 1;
  const int quad = lane >> 4;
  const int l16  = lane & 15;
  int bx, by;
  xcd_swizzle(gridDim.x, gridDim.y, bx, by);   // XCD-local tile chunks (A-panel L2 reuse)
  const int m0 = by * 128, n0 = bx * 128;

  auto issue = [&](int k0, int buf){
#pragma unroll
    for (int i = 0; i < 2; i++){     // A tile: 512 chunks of 16B (row = c>>2, q = c&3)
      int c = tid + i * 256;
      int row = c >> 2, q = c & 3;
      int qs = (q - ((row + (row >> 2)) & 3)) & 3;   // inverse chunk rotation
      async_ld16(A + (size_t)(m0 + row) * K + k0 + qs * 16,
                 smem + buf * 8192 + (i * 256 + wv * 64) * 16);
    }
#pragma unroll
    for (int i = 0; i < 2; i++){     // B tile
      int c = tid + i * 256;
      int row = c >> 2, q = c & 3;
      int qs = (q - ((row + (row >> 2)) & 3)) & 3;
      async_ld16(Bt + (size_t)(n0 + row) * K + k0 + qs * 16,
                 smem + 16384 + buf * 8192 + (i * 256 + wv * 64) * 16);
    }
  };

  i32x4 acc[4][4] = {};
  const int nk = K >> 6;
  issue(0, 0);

  const int ch = (((quad + (l16 & 3) + (l16 >> 2)) & 3)) * 16;

  for (int k = 0; k < nk; k++){
    const int cur = k & 1;
    if (k + 1 < nk){
      issue((k + 1) << 6, cur ^ 1);                       // prefetch next tile
      asm volatile("s_waitcnt vmcnt(4)" ::: "memory");    // tile-k loads landed; k+1 in flight
    } else {
      asm volatile("s_waitcnt vmcnt(0)" ::: "memory");
    }
    asm volatile("s_barrier" ::: "memory");               // tile-k visible to all waves

    const char* Ab = smem + cur * 8192;
    const char* Bb = smem + 16384 + cur * 8192;
    i32x4 af[4], bfr[4];
#pragma unroll
    for (int i = 0; i < 4; i++)
      af[i] = *(const i32x4*)(Ab + (wy * 64 + i * 16 + l16) * 64 + ch);
#pragma unroll
    for (int j = 0; j < 4; j++)
      bfr[j] = *(const i32x4*)(Bb + (wx * 64 + j * 16 + l16) * 64 + ch);
    asm volatile("s_waitcnt lgkmcnt(0)" ::: "memory");    // frags in regs
    asm volatile("s_barrier" ::: "memory");               // all reads of cur done

#pragma unroll
    for (int i = 0; i < 4; i++)
#pragma unroll
      for (int j = 0; j < 4; j++)
        acc[i][j] = mfma16i8(af[i], bfr[j], acc[i][j]);
  }
  __syncthreads();   // all waves out of the K-loop before stage overlay is used

  // ---- epilogue: 4 slices of 32 rows; LDS transpose -> coalesced wide loads/stores ----
  float (*stage)[132] = (float (*)[132])smem;   // 16896 B, overlays dead tile buffers
  const float sc = slot_scale(slots, sa_slot) * slot_scale(slots, sb_slot);
  const int col4 = (tid & 31) * 4;           // 0..124
  const int gc   = n0 + col4;
  const float4 bb = *(const float4*)&bias[gc];
  float gmax = 0.f;
#pragma unroll
  for (int i = 0; i < 4; i++){
#pragma unroll
    for (int j = 0; j < 4; j++)
#pragma unroll
      for (int r = 0; r < 4; r++)
        stage[wy * 16 + quad * 4 + r][wx * 64 + j * 16 + l16] = (float)acc[i][j][r];
    __syncthreads();
#pragma unroll
    for (int rr = 0; rr < 4; rr++){
      const int rl = rr * 8 + (tid >> 5);                       // 0..31
      const int gm = m0 + ((rl >> 4) * 64) + i * 16 + (rl & 15);
      float4 v = *(const float4*)&stage[rl][col4];
      v.x = v.x * sc + bb.x; v.y = v.y * sc + bb.y;
      v.z = v.z * sc + bb.z; v.w = v.w * sc + bb.w;
      if constexpr (EPI == 1){
        float4 rv = *(const float4*)&res[(size_t)gm * N + gc];
        v.x += rv.x; v.y += rv.y; v.z += rv.z; v.w += rv.w;
        *(float4*)&Cf[(size_t)gm * N + gc] = v;
      } else if constexpr (EPI == 2){
        float g0 = gelu_fast(v.x);
        float g1 = gelu_fast(v.y);
        float g2 = gelu_fast(v.z);
        float g3 = gelu_fast(v.w);
        gmax = fmaxf(gmax, fmaxf(fmaxf(fabsf(g0), fabsf(g1)), fmaxf(fabsf(g2), fabsf(g3))));
        uint2 o = {cvt_pk_bf16(g0, g1), cvt_pk_bf16(g2, g3)};   // HW RNE, 2 insts for 4 elems
        *(uint2*)&Cb[(size_t)gm * N + gc] = o;
      } else {
        *(float4*)&Cf[(size_t)gm * N + gc] = v;
      }
    }
    __syncthreads();
  }
  if constexpr (EPI == 2){
    for (int off = 32; off; off >>= 1) gmax = fmaxf(gmax, __shfl_xor(gmax, off));
    if (lane == 0) gm4[wv] = gmax;
    __syncthreads();
    if (tid == 0){
      float bm = fmaxf(fmaxf(gm4[0], gm4[1]), fmaxf(gm4[2], gm4[3]));
      scatter_amax(gmax_slots, gmax_slot, blockIdx.x + blockIdx.y * gridDim.x, bm);
    }
  }
}

// ---------------- attention: one block per (b,h), 13 waves, ONE q-tile per wave ----------------
// bh swizzled so the 12 heads sharing a batch's qkv panel land on the SAME XCD (768 = 8*96).
__launch_bounds__(832, 4)
__global__ void k_attention(const float* __restrict__ qkv, float* __restrict__ ctx,
                            unsigned* slots){
  __shared__ __align__(16) unsigned short Khi[208 * 72], Klo[208 * 72];   // 59,904 B
  __shared__ __align__(16) unsigned short Vhi[64 * 256], Vlo[64 * 256];   // 65,536 B (swizzled)
  __shared__ __align__(16) unsigned short Ps[13][2][16 * 40];             // 33,280 B (per-wave hi/lo)
  __shared__ float gm[13];

  const int bh = ((blockIdx.x & 7) * 96) + (blockIdx.x >> 3);   // XCD-local batch panels
  const int b = bh / NHEAD, h = bh % NHEAD;
  const float* base = qkv + (size_t)b * SEQ * NQKV;
  const int tid = threadIdx.x, lane = tid & 63, wv = tid >> 6;   // wv 0..12
  const int quad = lane >> 4, l16 = lane & 15;

  // ---- prefetch ALL K/V global data into registers, then convert+write LDS ----
  float4 kreg[4], vreg[5];
#pragma unroll
  for (int i = 0; i < 4; i++){
    int idx = tid + i * 832;                  // K: 208*16 = 3328 chunks (4*832 exact)
    int r = idx >> 4, c4 = (idx & 15) * 4;
    float4 v = {0.f, 0.f, 0.f, 0.f};
    if (r < SEQ) v = *(const float4*)(base + (size_t)r * NQKV + DMODEL + h * 64 + c4);
    kreg[i] = v;
  }
#pragma unroll
  for (int i = 0; i < 5; i++){
    int idx = tid + i * 832;                  // V: 232*16 = 3712 chunks (incl. zero pad)
    int s = idx >> 4, dg = (idx & 15) * 4;
    float4 v = {0.f, 0.f, 0.f, 0.f};
    if (idx < 232 * 16 && s < SEQ)
      v = *(const float4*)(base + (size_t)s * NQKV + 2 * DMODEL + h * 64 + dg);
    vreg[i] = v;
  }
#pragma unroll
  for (int i = 0; i < 4; i++){
    int idx = tid + i * 832;
    int r = idx >> 4, c4 = (idx & 15) * 4;
    float4 v = kreg[i];
    unsigned h01, l01, h23, l23;
    split_pk(v.x, v.y, h01, l01);
    split_pk(v.z, v.w, h23, l23);
    *(uint2*)(Khi + r * 72 + c4) = uint2{h01, h23};
    *(uint2*)(Klo + r * 72 + c4) = uint2{l01, l23};
  }
#pragma unroll
  for (int i = 0; i < 5; i++){
    int idx = tid + i * 832;
    if (idx < 232 * 16){
      int s = idx >> 4, dg = (idx & 15) * 4;
      float4 v = vreg[i];
      unsigned h01, l01, h23, l23;
      split_pk(v.x, v.y, h01, l01);
      split_pk(v.z, v.w, h23, l23);
      Vhi[vidx(dg + 0, s)] = (unsigned short)h01; Vhi[vidx(dg + 1, s)] = (unsigned short)(h01 >> 16);
      Vhi[vidx(dg + 2, s)] = (unsigned short)h23; Vhi[vidx(dg + 3, s)] = (unsigned short)(h23 >> 16);
      Vlo[vidx(dg + 0, s)] = (unsigned short)l01; Vlo[vidx(dg + 1, s)] = (unsigned short)(l01 >> 16);
      Vlo[vidx(dg + 2, s)] = (unsigned short)l23; Vlo[vidx(dg + 3, s)] = (unsigned short)(l23 >> 16);
    }
  }
  __syncthreads();    // the ONLY full-block barrier in the main body

  unsigned short* PsH = &Ps[wv][0][0];
  unsigned short* PsL = &Ps[wv][1][0];

  float gmax = 0.f;
  const int qt = wv;                 // one q-tile per wave
  {
    const int q0 = qt * 16;
    const int sq = q0 + l16;
    const bool valid = sq < SEQ;

    // Q fragments straight from global (A-layout: m=l16, k=quad*8+j), split hi/lo packed
    bf16x8 aqh[2], aql[2];
    const float* qrow = base + (size_t)(valid ? sq : 0) * NQKV + h * 64;
#pragma unroll
    for (int ks = 0; ks < 2; ks++){
      float4 v0 = {0,0,0,0}, v1 = {0,0,0,0};
      if (valid){
        v0 = *(const float4*)(qrow + ks * 32 + quad * 8);
        v1 = *(const float4*)(qrow + ks * 32 + quad * 8 + 4);
      }
      unsigned* ah = (unsigned*)&aqh[ks];
      unsigned* al = (unsigned*)&aql[ks];
      split_pk(v0.x, v0.y, ah[0], al[0]);
      split_pk(v0.z, v0.w, ah[1], al[1]);
      split_pk(v1.x, v1.y, ah[2], al[2]);
      split_pk(v1.z, v1.w, ah[3], al[3]);
    }

    // ---- S = Q K^T / 8 : 13 independent MFMA chains ----
    f32x4 sacc[13];
    __builtin_amdgcn_s_setprio(1);
#pragma unroll
    for (int t = 0; t < 13; t++){
      f32x4 a = {0.f, 0.f, 0.f, 0.f};
#pragma unroll
      for (int ks = 0; ks < 2; ks++){
        bf16x8 bkh = *(const bf16x8*)(Khi + (t * 16 + l16) * 72 + ks * 32 + quad * 8);
        bf16x8 bkl = *(const bf16x8*)(Klo + (t * 16 + l16) * 72 + ks * 32 + quad * 8);
        a = mfma16(aqh[ks], bkh, a);
        a = mfma16(aqh[ks], bkl, a);
        a = mfma16(aql[ks], bkh, a);
      }
      sacc[t] = a;
    }
    __builtin_amdgcn_s_setprio(0);

    // ---- softmax in registers: lane holds rows q=quad*4+r, cols s=t*16+l16 ----
    float mx[4] = {-1e30f, -1e30f, -1e30f, -1e30f};
#pragma unroll
    for (int t = 0; t < 13; t++){
      bool dead = (t == 12) && (l16 >= 4);   // key col >= 196
#pragma unroll
      for (int r = 0; r < 4; r++){
        float v = dead ? -1e30f : sacc[t][r] * 0.125f;
        sacc[t][r] = v;
        mx[r] = fmaxf(mx[r], v);
      }
    }
#pragma unroll
    for (int off = 1; off < 16; off <<= 1)
#pragma unroll
      for (int r = 0; r < 4; r++) mx[r] = fmaxf(mx[r], __shfl_xor(mx[r], off));
    float sum[4] = {0.f, 0.f, 0.f, 0.f};
#pragma unroll
    for (int t = 0; t < 13; t++)
#pragma unroll
      for (int r = 0; r < 4; r++){
        float e = __expf(sacc[t][r] - mx[r]);
        sacc[t][r] = e; sum[r] += e;
      }
#pragma unroll
    for (int off = 1; off < 16; off <<= 1)
#pragma unroll
      for (int r = 0; r < 4; r++) sum[r] += __shfl_xor(sum[r], off);
    float inv[4];
#pragma unroll
    for (int r = 0; r < 4; r++) inv[r] = 1.0f / sum[r];

    // ---- O = P V : per-ks transpose C->A layout through per-wave scratch, no barrier ----
    f32x4 oacc[4] = {};
#pragma unroll
    for (int ks = 0; ks < 7; ks++){
      const int t0 = 2 * ks, t1 = 2 * ks + 1;
#pragma unroll
      for (int r = 0; r < 4; r++){
        int row = quad * 4 + r;
        float a = sacc[t0][r] * inv[r];
        float c = (t1 < 13) ? sacc[t1][r] * inv[r] : 0.f;   // bf16(0)=0 handles the pad
        unsigned hp, lp;
        split_pk(a, c, hp, lp);
        PsH[row * 40 + l16]      = (unsigned short)hp;
        PsH[row * 40 + 16 + l16] = (unsigned short)(hp >> 16);
        PsL[row * 40 + l16]      = (unsigned short)lp;
        PsL[row * 40 + 16 + l16] = (unsigned short)(lp >> 16);
      }
      __builtin_amdgcn_wave_barrier();   // keep compiler from reordering the RAW through LDS
      bf16x8 aph = *(const bf16x8*)(PsH + l16 * 40 + quad * 8);
      bf16x8 apl = *(const bf16x8*)(PsL + l16 * 40 + quad * 8);
      __builtin_amdgcn_s_setprio(1);
#pragma unroll
      for (int n = 0; n < 4; n++){
        bf16x8 bvh = *(const bf16x8*)(Vhi + vidx(n * 16 + l16, ks * 32 + quad * 8));
        bf16x8 bvl = *(const bf16x8*)(Vlo + vidx(n * 16 + l16, ks * 32 + quad * 8));
        oacc[n] = mfma16(aph, bvh, oacc[n]);
        oacc[n] = mfma16(aph, bvl, oacc[n]);
        oacc[n] = mfma16(apl, bvh, oacc[n]);
      }
      __builtin_amdgcn_s_setprio(0);
      __builtin_amdgcn_wave_barrier();   // reads of this slice complete before next-iter writes
    }

    // ---- store ctx (C-layout: row=quad*4+r, col=n*16+l16) + absmax ----
#pragma unroll
    for (int r = 0; r < 4; r++){
      int srow = q0 + quad * 4 + r;
      if (srow < SEQ){
#pragma unroll
        for (int n = 0; n < 4; n++){
          float v = oacc[n][r];
          ctx[((size_t)(b * SEQ + srow)) * DMODEL + h * 64 + n * 16 + l16] = v;
          gmax = fmaxf(gmax, fabsf(v));
        }
      }
    }
  }
  for (int off = 32; off; off >>= 1) gmax = fmaxf(gmax, __shfl_xor(gmax, off));
  if (lane == 0) gm[wv] = gmax;
  __syncthreads();
  if (tid == 0){
    float bm = 0.f;
#pragma unroll
    for (int i = 0; i < 13; i++) bm = fmaxf(bm, gm[i]);
    scatter_amax(slots, SL_CTX, blockIdx.x, bm);
  }
}

// ---------------- launch ----------------
extern "C" void kernel_launch(void* const* d_in, const int* in_sizes, int n_in,
                              void* d_out, int out_size, void* d_ws, size_t ws_size,
                              hipStream_t stream)
{
  const float* x     = (const float*)d_in[0];
  const float* ln1_g = (const float*)d_in[1];
  const float* ln1_b = (const float*)d_in[2];
  const float* ln2_g = (const float*)d_in[3];
  const float* ln2_b = (const float*)d_in[4];
  const float* w_qkv = (const float*)d_in[5];
  const float* b_qkv = (const float*)d_in[6];
  const float* w_o   = (const float*)d_in[7];
  const float* b_o   = (const float*)d_in[8];
  const float* w1    = (const float*)d_in[9];
  const float* b1    = (const float*)d_in[10];
  const float* w2    = (const float*)d_in[11];
  const float* b2    = (const float*)d_in[12];

  char* ws = (char*)d_ws;
  size_t off = 0;
  unsigned* slots = (unsigned*)ws;                 off += SLOTS_U32 * 4;   // 16 KB scattered slots
  float2* stats = (float2*)(ws + off);             off += (size_t)NTOK * 8; // 100 KB LN row stats
  char* wqkvT = (char*)(ws + off); off += (size_t)NQKV  * DMODEL;
  char* woT   = (char*)(ws + off); off += (size_t)DMODEL* DMODEL;
  char* w1T   = (char*)(ws + off); off += (size_t)MMLP  * DMODEL;
  char* w2T   = (char*)(ws + off); off += (size_t)DMODEL* MMLP;
  off = (off + 255) & ~(size_t)255;
  float* t1    = (float*)(ws + off);               off += (size_t)NTOK * DMODEL * 4;
  char*  t1q   = (char*)(ws + off);                off += (size_t)NTOK * DMODEL;
  off = (off + 255) & ~(size_t)255;
  float* qkv   = (float*)(ws + off);               off += (size_t)NTOK * NQKV * 4;
  float* xmid  = (float*)(ws + off);               off += (size_t)NTOK * DMODEL * 4;
  // FC1 bf16 output (77.07 MB) + its int8 quant (38.54 MB) exactly fill the qkv region (115.6 MB)
  unsigned short* h1 = (unsigned short*)qkv;
  char* h1q = (char*)qkv + (size_t)NTOK * MMLP * 2;
  float* outp = (float*)d_out;

  hipMemsetAsync(slots, 0, SLOTS_U32 * 4, stream);

  // weight absmax (896 blocks) || LN1 stats+absmax (3136 blocks)
  k_prep1<<<4032, 256, 0, stream>>>(w_qkv, w_o, w1, w2, x, ln1_g, ln1_b, stats, slots);
  // weight quant-transpose (6912) || LN1 quant -> t1q (3136)
  k_prep2<<<10048, 256, 0, stream>>>(w_qkv, w_o, w1, w2, wqkvT, woT, w1T, w2T,
                                     x, ln1_g, ln1_b, stats, t1q, slots);

  k_gemm<0><<<dim3(NQKV / 128, NTOK / 128), 256, 0, stream>>>(
      t1q, wqkvT, b_qkv, nullptr, qkv, nullptr, slots, SL_LN1, SL_WQKV, nullptr, 0,
      NTOK, NQKV, DMODEL);

  // attention -> ctx (t1) + absmax
  k_attention<<<NBATCH * NHEAD, 832, 0, stream>>>(qkv, t1, slots);
  {
    int n4 = NTOK * DMODEL / 4;
    k_quant_act<<<2048, 256, 0, stream>>>(t1, (unsigned*)t1q, n4, slots, SL_CTX);
  }
  // O-proj + residual -> xmid
  k_gemm<1><<<dim3(DMODEL / 128, NTOK / 128), 256, 0, stream>>>(
      t1q, woT, b_o, x, xmid, nullptr, slots, SL_CTX, SL_WO, nullptr, 0,
      NTOK, DMODEL, DMODEL);

  // LN2 (stats-split) -> quant -> FC1(+gelu->bf16) -> quant -> FC2 + residual -> out
  k_ln_stats<<<NTOK / 4, 256, 0, stream>>>(xmid, ln2_g, ln2_b, stats, slots, SL_LN2);
  k_ln_quant<<<NTOK / 4, 256, 0, stream>>>(xmid, ln2_g, ln2_b, stats, t1q, slots, SL_LN2);

  k_gemm<2><<<dim3(MMLP / 128, NTOK / 128), 256, 0, stream>>>(
      t1q, w1T, b1, nullptr, nullptr, h1, slots, SL_LN2, SL_W1, slots, SL_GELU,
      NTOK, MMLP, DMODEL);
  {
    int n4 = NTOK * MMLP / 4;
    k_quant_bf16_i8<<<2048, 256, 0, stream>>>(h1, (unsigned*)h1q, n4, slots, SL_GELU);
  }
  k_gemm<1><<<dim3(DMODEL / 128, NTOK / 128), 256, 0, stream>>>(
      h1q, w2T, b2, xmid, outp, nullptr, slots, SL_GELU, SL_W2, nullptr, 0,
      NTOK, DMODEL, MMLP);
}